// Round 11
// baseline (4867.234 us; speedup 1.0000x reference)
//
#include <hip/hip_runtime.h>
#include <hip/hip_fp16.h>
#include <cstdint>
#include <cstddef>

#define T_STEPS 512
#define HID 40
#define NSLOT 144          // gate slots: r=0..47, z=48..95, n=96..143 (unit u valid if u%48<40)
#define NT 9               // 144/16 n-tiles
#define FRAGB 3840         // frag bytes per (blk,step): 6 full tiles*512 + 3 half tiles*256

typedef _Float16 half8  __attribute__((ext_vector_type(8)));
typedef _Float16 fp16x4 __attribute__((ext_vector_type(4)));
typedef float    f32x4  __attribute__((ext_vector_type(4)));

__device__ __forceinline__ void wavesync() { asm volatile("s_waitcnt lgkmcnt(0)" ::: "memory"); }
__device__ __forceinline__ float sigm(float x) { return 1.f / (1.f + __expf(-x)); }

// byte offset of this lane's b64 frag within a (blk,step) FRAGB block
__device__ __forceinline__ int frag_off(int t, int g, int r) {
    if (t % 3 == 2) return 3072 + (t / 3) * 256 + (g * 8 + (r & 7)) * 8;  // half tile (units 32..39)
    return (t - t / 3) * 512 + (g * 16 + r) * 8;                          // full tile
}

// ---------------- weight prep (cold) ----------------
// wpad[144][KP] f16 + bpad[144] f32 from w[120][K], b[120] with gate-slot padding.
__global__ __launch_bounds__(256) void prep_gate_pad(
    const float* __restrict__ w, const float* __restrict__ b, int K, int KP,
    __half* __restrict__ wpad, float* __restrict__ bpad)
{
    const int idx = blockIdx.x * 256 + threadIdx.x;
    if (idx >= NSLOT * KP) return;
    const int s = idx / KP, k = idx % KP;
    const int gi = s / 48, u = s % 48;
    float v = (u < HID && k < K) ? w[(gi * HID + u) * K + k] : 0.f;
    wpad[idx] = __float2half(v);
    if (k == 0) bpad[s] = (u < HID) ? b[gi * HID + u] : 0.f;
}

// folded wih_eff = wih@w2 (+ bias fold), slot-padded
__global__ __launch_bounds__(256) void prep_eff_pad(
    const float* __restrict__ g_wih, const float* __restrict__ g_bih,
    const float* __restrict__ w2, const float* __restrict__ b2,
    __half* __restrict__ wpad, float* __restrict__ bpad)
{
    const int li = blockIdx.y;
    const int idx = blockIdx.x * 256 + threadIdx.x;
    if (idx >= NSLOT * 64) return;
    const int s = idx >> 6, k = idx & 63;
    const int gi = s / 48, u = s % 48;
    float v = 0.f;
    if (u < HID && k < HID) {
        const float* wrow = g_wih + ((size_t)(li + 1) * 120 + gi * HID + u) * HID;
        for (int j = 0; j < HID; ++j) v += wrow[j] * w2[((size_t)li * HID + j) * HID + k];
    }
    wpad[(size_t)li * NSLOT * 64 + idx] = __float2half(v);
    if (k == 0) {
        float bv = 0.f;
        if (u < HID) {
            const float* wrow = g_wih + ((size_t)(li + 1) * 120 + gi * HID + u) * HID;
            bv = g_bih[(li + 1) * 120 + gi * HID + u];
            for (int j = 0; j < HID; ++j) bv += wrow[j] * b2[(size_t)li * HID + j];
        }
        bpad[li * NSLOT + s] = bv;
    }
}

__global__ __launch_bounds__(256) void prep_w1_pad(
    const float* __restrict__ w1, const float* __restrict__ b1,
    __half* __restrict__ wpad, float* __restrict__ bpad)
{
    const int li = blockIdx.y;
    const int idx = blockIdx.x * 256 + threadIdx.x;
    if (idx >= 48 * 64) return;
    const int n = idx >> 6, k = idx & 63;
    float v = (n < HID && k < HID) ? w1[((size_t)li * HID + n) * HID + k] : 0.f;
    wpad[(size_t)li * 48 * 64 + idx] = __float2half(v);
    if (k == 0) bpad[li * 48 + n] = (n < HID) ? b1[li * HID + n] : 0.f;
}

// ---------------- MFMA precompute -> fragment-layout xp ----------------
// MODE 0: fp32 x [e][T][20], K=20 pad 32 (1 kstep). MODE 1: h rows in xpf blocks, K pad 64.
// MODE 2: MLP GEMM1 (w1pad) + leaky + swizzled-LDS transpose + gates GEMM (R7-verified machinery).
// Output per task (blk,ts): 9 C-fragment tiles + bih added, f16, compact layout (frag_off).
// MODE 1/2 read the h region of the SAME block they overwrite (wave-local RAW, ordered).
template<int MODE>
__global__ __launch_bounds__(256) void precomp_mfma(
    const void* in_, char* xpf,
    const _Float16* __restrict__ wpad,   // [144][KP]
    const float* __restrict__ bpad,      // [144]
    const _Float16* __restrict__ w1pad,  // [48][64] (MODE 2)
    const float* __restrict__ b1pad,     // [48]     (MODE 2)
    int ntasks)
{
    __shared__ _Float16 s_v[4][1024];
    const int tid = threadIdx.x, wid = tid >> 6, lane = tid & 63;
    const int g = lane >> 4, r = lane & 15;
    constexpr int KP = (MODE == 0) ? 32 : 64;
    constexpr int NKS = KP / 32;

    half8 bw[NT][NKS];
    float bi[NT];
    #pragma unroll
    for (int t = 0; t < NT; ++t) {
        #pragma unroll
        for (int ks = 0; ks < NKS; ++ks)
            bw[t][ks] = *reinterpret_cast<const half8*>(wpad + (t * 16 + r) * KP + ks * 32 + g * 8);
        bi[t] = bpad[t * 16 + r];
    }

    half8 b1f[3][2];
    float b1v[3];
    char* myv = (char*)&s_v[wid][0];
    if constexpr (MODE == 2) {
        #pragma unroll
        for (int t = 0; t < 3; ++t) {
            #pragma unroll
            for (int ks = 0; ks < 2; ++ks)
                b1f[t][ks] = *reinterpret_cast<const half8*>(w1pad + (t * 16 + r) * 64 + ks * 32 + g * 8);
            b1v[t] = b1pad[t * 16 + r];
        }
        uint4 z = {0u, 0u, 0u, 0u};
        *reinterpret_cast<uint4*>(myv + lane * 32) = z;
        *reinterpret_cast<uint4*>(myv + lane * 32 + 16) = z;
        wavesync();
    }

    const int w0 = blockIdx.x * 4 + wid;
    const int wstride = gridDim.x * 4;
    const int sw = (r & 7) << 4;

    for (int task = w0; task < ntasks; task += wstride) {
        const int blk = task >> 9, ts = task & 511;
        char* blkbase = xpf + ((size_t)blk * T_STEPS + ts) * FRAGB;

        half8 a0, a1;
        if constexpr (MODE == 0) {
            const float* xr = (const float*)in_ + ((size_t)(blk * 16 + r) * T_STEPS + ts) * 20;
            #pragma unroll
            for (int j = 0; j < 8; ++j) { a0[j] = (_Float16)0.f; a1[j] = (_Float16)0.f; }
            if (g < 2) {
                const float4 v0 = *reinterpret_cast<const float4*>(xr + g * 8);
                const float4 v1 = *reinterpret_cast<const float4*>(xr + g * 8 + 4);
                a0[0]=(_Float16)v0.x; a0[1]=(_Float16)v0.y; a0[2]=(_Float16)v0.z; a0[3]=(_Float16)v0.w;
                a0[4]=(_Float16)v1.x; a0[5]=(_Float16)v1.y; a0[6]=(_Float16)v1.z; a0[7]=(_Float16)v1.w;
            } else if (g == 2) {
                const float4 v0 = *reinterpret_cast<const float4*>(xr + 16);
                a0[0]=(_Float16)v0.x; a0[1]=(_Float16)v0.y; a0[2]=(_Float16)v0.z; a0[3]=(_Float16)v0.w;
            }
        } else {
            const char* hrow = (const char*)in_ + ((size_t)blk * T_STEPS + ts) * FRAGB + r * 128;
            a0 = *reinterpret_cast<const half8*>(hrow + g * 16);
            a1 = *reinterpret_cast<const half8*>(hrow + 64 + g * 16);
        }

        if constexpr (MODE == 2) {
            #pragma unroll
            for (int t = 0; t < 3; ++t) {
                f32x4 acc = {0.f, 0.f, 0.f, 0.f};
                acc = __builtin_amdgcn_mfma_f32_16x16x32_f16(a1, b1f[t][1], acc, 0, 0, 0);
                acc = __builtin_amdgcn_mfma_f32_16x16x32_f16(a0, b1f[t][0], acc, 0, 0, 0);
                const int n2 = (t * 16 + r) * 2;
                #pragma unroll
                for (int reg = 0; reg < 4; ++reg) {
                    const int m = g * 4 + reg;
                    float v = acc[reg] + b1v[t];
                    v = v > 0.f ? v : 0.01f * v;
                    *reinterpret_cast<_Float16*>(myv + m * 128 + (n2 ^ ((m & 7) << 4))) = (_Float16)v;
                }
            }
            wavesync();
            a0 = *reinterpret_cast<const half8*>(myv + r * 128 + ((g * 16) ^ sw));
            a1 = *reinterpret_cast<const half8*>(myv + r * 128 + ((64 + g * 16) ^ sw));
        }

        #pragma unroll
        for (int t = 0; t < NT; ++t) {
            f32x4 acc = {0.f, 0.f, 0.f, 0.f};
            if constexpr (NKS == 2)
                acc = __builtin_amdgcn_mfma_f32_16x16x32_f16(a1, bw[t][1], acc, 0, 0, 0);
            acc = __builtin_amdgcn_mfma_f32_16x16x32_f16(a0, bw[t][0], acc, 0, 0, 0);
            fp16x4 o;
            #pragma unroll
            for (int reg = 0; reg < 4; ++reg) o[reg] = (_Float16)(acc[reg] + bi[t]);
            if (t % 3 == 2) {
                if (r < 8)
                    *reinterpret_cast<fp16x4*>(blkbase + 3072 + (t / 3) * 256 + (g * 8 + r) * 8) = o;
            } else {
                *reinterpret_cast<fp16x4*>(blkbase + (t - t / 3) * 512 + lane * 8) = o;
            }
        }
    }
}

// ---------------- MFMA recurrence: 16 elements per wave ----------------
// C layout (R7-verified): n = t*16 + (lane&15), m = (lane>>4)*4 + reg.
// Lane (g,r) holds, for elems m=g*4+0..3, units {r, 16+r, 32+r(if r<8)} with r,z,n
// gate-sums all IN-LANE (144-slot arrangement) -> activation needs no cross-lane ops.
// h transposed back to A layout via XOR-swizzled LDS tile each step; h also written
// (in-place) into the consumed frag block for the next layer's precomp.
template<bool WRITE_ALL>
__global__ __launch_bounds__(64) void gru_rec(
    char* xpf,
    const _Float16* __restrict__ whhpad,  // [144][64]
    const float* __restrict__ bhhpad)     // [144]
{
    __shared__ __align__(16) char h_tile[2048];   // [16 elems][64 units] f16, XOR-swizzled rows
    const int lane = threadIdx.x;
    const int g = lane >> 4, r = lane & 15;
    const int sw = (r & 7) << 4;

    half8 bw[NT][2];
    float bb[NT];
    #pragma unroll
    for (int t = 0; t < NT; ++t) {
        bw[t][0] = *reinterpret_cast<const half8*>(whhpad + (t * 16 + r) * 64 + g * 8);
        bw[t][1] = *reinterpret_cast<const half8*>(whhpad + (t * 16 + r) * 64 + 32 + g * 8);
        bb[t] = bhhpad[t * 16 + r];
    }

    {
        uint4 z = {0u, 0u, 0u, 0u};
        *reinterpret_cast<uint4*>(h_tile + lane * 32) = z;
        *reinterpret_cast<uint4*>(h_tile + lane * 32 + 16) = z;
    }
    wavesync();

    char* base = xpf + (size_t)blockIdx.x * T_STEPS * FRAGB;

    uint2 f0[NT], f1[NT];
    #pragma unroll
    for (int t = 0; t < NT; ++t) {
        f0[t] = *reinterpret_cast<const uint2*>(base + frag_off(t, g, r));
        f1[t] = *reinterpret_cast<const uint2*>(base + FRAGB + frag_off(t, g, r));
    }

    float hprev[3][4] = {};
    half8 a0 = *reinterpret_cast<const half8*>(h_tile + r * 128 + ((g * 16) ^ sw));
    half8 a1 = *reinterpret_cast<const half8*>(h_tile + r * 128 + ((64 + g * 16) ^ sw));

    for (int t = 0; t < T_STEPS; ++t) {
        // prefetch frags for t+2 (stays in flight; wavesync never touches vmcnt)
        uint2 fn[NT];
        if (t + 2 < T_STEPS) {
            const char* pb = base + (size_t)(t + 2) * FRAGB;
            #pragma unroll
            for (int tt = 0; tt < NT; ++tt)
                fn[tt] = *reinterpret_cast<const uint2*>(pb + frag_off(tt, g, r));
        } else {
            #pragma unroll
            for (int tt = 0; tt < NT; ++tt) fn[tt] = f1[tt];
        }

        // per unit-group: 6 MFMAs (r,z,n tiles) then lane-local activation
        #pragma unroll
        for (int ui = 0; ui < 3; ++ui) {
            f32x4 aR = {0.f,0.f,0.f,0.f}, aZ = {0.f,0.f,0.f,0.f}, aN = {0.f,0.f,0.f,0.f};
            aR = __builtin_amdgcn_mfma_f32_16x16x32_f16(a1, bw[ui][1], aR, 0, 0, 0);
            aR = __builtin_amdgcn_mfma_f32_16x16x32_f16(a0, bw[ui][0], aR, 0, 0, 0);
            aZ = __builtin_amdgcn_mfma_f32_16x16x32_f16(a1, bw[3 + ui][1], aZ, 0, 0, 0);
            aZ = __builtin_amdgcn_mfma_f32_16x16x32_f16(a0, bw[3 + ui][0], aZ, 0, 0, 0);
            aN = __builtin_amdgcn_mfma_f32_16x16x32_f16(a1, bw[6 + ui][1], aN, 0, 0, 0);
            aN = __builtin_amdgcn_mfma_f32_16x16x32_f16(a0, bw[6 + ui][0], aN, 0, 0, 0);

            if (ui < 2 || r < 8) {
                const fp16x4 xR = __builtin_bit_cast(fp16x4, f0[ui]);
                const fp16x4 xZ = __builtin_bit_cast(fp16x4, f0[3 + ui]);
                const fp16x4 xN = __builtin_bit_cast(fp16x4, f0[6 + ui]);
                #pragma unroll
                for (int reg = 0; reg < 4; ++reg) {
                    const float rs = (float)xR[reg] + aR[reg] + bb[ui];
                    const float zs = (float)xZ[reg] + aZ[reg] + bb[3 + ui];
                    const float sh = aN[reg] + bb[6 + ui];
                    const float rr = sigm(rs);
                    const float zz = sigm(zs);
                    const float pre = (float)xN[reg] + rr * sh;
                    const float ex  = __expf(-2.f * pre);
                    const float nn  = (1.f - ex) / (1.f + ex);
                    const float h   = (1.f - zz) * nn + zz * hprev[ui][reg];
                    hprev[ui][reg] = h;
                    const int m = g * 4 + reg, u = ui * 16 + r;
                    *reinterpret_cast<_Float16*>(h_tile + m * 128 + ((u * 2) ^ ((m & 7) << 4))) =
                        (_Float16)h;
                }
            }
        }
        wavesync();   // h_tile writes visible (wave-local)

        a0 = *reinterpret_cast<const half8*>(h_tile + r * 128 + ((g * 16) ^ sw));
        a1 = *reinterpret_cast<const half8*>(h_tile + r * 128 + ((64 + g * 16) ^ sw));

        if (WRITE_ALL || t == T_STEPS - 1) {
            // write h rows (un-swizzled) into the consumed frag block for next layer
            const int m = lane >> 2, c = lane & 3, swm = (m & 7) << 4;
            const uint4 v0 = *reinterpret_cast<const uint4*>(h_tile + m * 128 + ((c * 32) ^ swm));
            const uint4 v1 = *reinterpret_cast<const uint4*>(h_tile + m * 128 + ((c * 32 + 16) ^ swm));
            char* dst = base + (size_t)t * FRAGB + m * 128 + c * 32;
            *reinterpret_cast<uint4*>(dst) = v0;
            *reinterpret_cast<uint4*>(dst + 16) = v1;
        }

        #pragma unroll
        for (int tt = 0; tt < NT; ++tt) { f0[tt] = f1[tt]; f1[tt] = fn[tt]; }
    }
}

// ---------------- head ----------------
__global__ __launch_bounds__(256) void final_head(
    const char* __restrict__ xpf, float* __restrict__ outp,
    const float* __restrict__ w1, const float* __restrict__ b1,
    const float* __restrict__ wl, const float* __restrict__ bl, int n)
{
    __shared__ float s_w1[HID][HID + 1];
    __shared__ float s_b1[HID];
    __shared__ float s_wl[HID];
    for (int i = threadIdx.x; i < HID * HID; i += 256) s_w1[i / HID][i % HID] = w1[i];
    if (threadIdx.x < HID) { s_b1[threadIdx.x] = b1[threadIdx.x]; s_wl[threadIdx.x] = wl[threadIdx.x]; }
    __syncthreads();
    const int e = blockIdx.x * 256 + threadIdx.x;
    if (e >= n) return;

    const _Float16* hr = (const _Float16*)(xpf +
        ((size_t)((e >> 4) * T_STEPS + T_STEPS - 1)) * FRAGB + (size_t)(e & 15) * 128);
    float h[HID];
    #pragma unroll
    for (int q = 0; q < 5; ++q) {
        const half8 v = *reinterpret_cast<const half8*>(hr + q * 8);
        #pragma unroll
        for (int j = 0; j < 8; ++j) h[q * 8 + j] = (float)v[j];
    }

    float acc = bl[0];
    #pragma unroll
    for (int u = 0; u < HID; ++u) {
        float a = s_b1[u];
        #pragma unroll
        for (int d = 0; d < HID; ++d) a += s_w1[u][d] * h[d];
        a = a > 0.f ? a : 0.01f * a;
        acc += a * s_wl[u];
    }
    outp[e] = 1.f / (1.f + __expf(-acc));
}

extern "C" void kernel_launch(void* const* d_in, const int* in_sizes, int n_in,
                              void* d_out, int out_size, void* d_ws, size_t ws_size,
                              hipStream_t stream)
{
    const float* x      = (const float*)d_in[0];
    const float* g0_wih = (const float*)d_in[1];
    const float* g0_whh = (const float*)d_in[2];
    const float* g0_bih = (const float*)d_in[3];
    const float* g0_bhh = (const float*)d_in[4];
    const float* g_wih  = (const float*)d_in[5];   // [4,120,40]
    const float* g_whh  = (const float*)d_in[6];   // [4,120,40]
    const float* g_bih  = (const float*)d_in[7];   // [4,120]
    const float* g_bhh  = (const float*)d_in[8];   // [4,120]
    const float* mlp_w1 = (const float*)d_in[9];   // [4,40,40]
    const float* mlp_b1 = (const float*)d_in[10];  // [4,40]
    const float* mlp_w2 = (const float*)d_in[11];  // [3,40,40]
    const float* mlp_b2 = (const float*)d_in[12];  // [3,40]
    const float* w_last = (const float*)d_in[13];  // [1,40]
    const float* b_last = (const float*)d_in[14];  // [1]

    const int B = in_sizes[0] / (T_STEPS * 20);
    float* out = (float*)d_out;

    // ws layout (halfs): g0pad 144*32 | g1pad 144*64 | effpad 3*144*64 | w1pad 3*48*64 | whhpad 5*144*64
    __half* wsz    = (__half*)d_ws;
    __half* g0pad  = wsz;                        // 4608
    __half* g1pad  = g0pad + 4608;               // 9216
    __half* effpad = g1pad + 9216;               // 27648
    __half* w1pad  = effpad + 27648;             // 9216
    __half* whhpad = w1pad + 9216;               // 46080
    float*  fb     = (float*)(whhpad + 46080);
    float* bih0 = fb;            // 144
    float* bih1 = bih0 + 144;    // 144
    float* bihE = bih1 + 144;    // 432
    float* b1p  = bihE + 432;    // 144
    float* bhhp = b1p + 144;     // 720
    char* xpf = (char*)d_ws + ((((char*)(bhhp + 720) - (char*)d_ws) + 4095) & ~(size_t)4095);
    const size_t ws_rem = ws_size - (size_t)(xpf - (char*)d_ws);

    prep_gate_pad<<<dim3(18), dim3(256), 0, stream>>>(g0_wih, g0_bih, 20, 32, g0pad, bih0);
    prep_gate_pad<<<dim3(36), dim3(256), 0, stream>>>(g_wih, g_bih, 40, 64, g1pad, bih1);
    prep_eff_pad<<<dim3(36, 3), dim3(256), 0, stream>>>(g_wih, g_bih, mlp_w2, mlp_b2, effpad, bihE);
    prep_w1_pad<<<dim3(12, 3), dim3(256), 0, stream>>>(mlp_w1, mlp_b1, w1pad, b1p);
    prep_gate_pad<<<dim3(36), dim3(256), 0, stream>>>(g0_whh, g0_bhh, 40, 64, whhpad, bhhp);
    for (int li = 0; li < 4; ++li)
        prep_gate_pad<<<dim3(36), dim3(256), 0, stream>>>(
            g_whh + li * 4800, g_bhh + li * 120, 40, 64,
            whhpad + (size_t)(1 + li) * 9216, bhhp + (1 + li) * 144);

    // per-element frag footprint: 512 steps * 240B = 122880 B
    int CB = B;
    while ((size_t)CB * 122880 > ws_rem && CB > 16) CB >>= 1;

    for (int c = 0; c < B; c += CB) {
        const int nblkC = CB / 16;
        const int ntasks = nblkC * T_STEPS;
        const dim3 pgrd(1024), pblk(256);
        const dim3 rgrd(nblkC), rblk(64);

        precomp_mfma<0><<<pgrd, pblk, 0, stream>>>(
            x + (size_t)c * T_STEPS * 20, xpf, (const _Float16*)g0pad, bih0,
            nullptr, nullptr, ntasks);
        gru_rec<true><<<rgrd, rblk, 0, stream>>>(xpf, (const _Float16*)whhpad, bhhp);

        precomp_mfma<1><<<pgrd, pblk, 0, stream>>>(
            xpf, xpf, (const _Float16*)g1pad, bih1, nullptr, nullptr, ntasks);
        gru_rec<true><<<rgrd, rblk, 0, stream>>>(
            xpf, (const _Float16*)(whhpad + 9216), bhhp + 144);

        for (int li = 0; li < 3; ++li) {
            precomp_mfma<2><<<pgrd, pblk, 0, stream>>>(
                xpf, xpf, (const _Float16*)(effpad + (size_t)li * 9216), bihE + li * 144,
                (const _Float16*)(w1pad + (size_t)li * 3072), b1p + li * 48, ntasks);
            if (li < 2)
                gru_rec<true><<<rgrd, rblk, 0, stream>>>(
                    xpf, (const _Float16*)(whhpad + (size_t)(2 + li) * 9216), bhhp + (2 + li) * 144);
            else
                gru_rec<false><<<rgrd, rblk, 0, stream>>>(
                    xpf, (const _Float16*)(whhpad + (size_t)4 * 9216), bhhp + 4 * 144);
        }

        final_head<<<dim3((CB + 255) / 256), dim3(256), 0, stream>>>(
            xpf, out + c, mlp_w1 + 3 * 1600, mlp_b1 + 3 * 40, w_last, b_last, CB);
    }
}

// Round 13
// 3071.961 us; speedup vs baseline: 1.5844x; 1.5844x over previous
//
#include <hip/hip_runtime.h>
#include <hip/hip_fp16.h>
#include <cstdint>
#include <cstddef>

#define T_STEPS 512
#define HID 40
#define GATES 120

typedef _Float16 half8 __attribute__((ext_vector_type(8)));
typedef _Float16 fp16x2 __attribute__((ext_vector_type(2)));
typedef float f32x4 __attribute__((ext_vector_type(4)));

// Single-wave-block "barrier": lanes lockstep; only LDS completion ordering needed.
__device__ __forceinline__ void wavesync() { asm volatile("s_waitcnt lgkmcnt(0)" ::: "memory"); }
__device__ __forceinline__ float bperm(int srclane, float v) {
    return __int_as_float(__builtin_amdgcn_ds_bpermute(srclane << 2, __float_as_int(v)));
}
__device__ __forceinline__ float sigm(float x) { return 1.f / (1.f + __expf(-x)); }

// parse-time-constant fp16x2 extraction from a half8
template<int J>
__device__ __forceinline__ fp16x2 ext2(half8 v) {
    return __builtin_shufflevector(v, v, 2 * J, 2 * J + 1);
}

#if __has_builtin(__builtin_amdgcn_fdot2)
__device__ __forceinline__ float fdot2(fp16x2 a, fp16x2 b, float c) {
    return __builtin_amdgcn_fdot2(a, b, c, false);
}
#else
__device__ __forceinline__ float fdot2(fp16x2 a, fp16x2 b, float c) {
    return c + (float)a[0] * (float)b[0] + (float)a[1] * (float)b[1];
}
#endif

// ---------------- weight prep (run once, tiny) ----------------
__global__ __launch_bounds__(256) void prep_pad(
    const float* __restrict__ w, const float* __restrict__ b,
    __half* __restrict__ out, int N, int K, int KPAD)
{
    const int idx = blockIdx.x * 256 + threadIdx.x;
    const int n = idx / KPAD, k = idx - n * KPAD;
    float v = 0.f;
    if (n < N) {
        if (k < K) v = w[n * K + k];
        else if (k == KPAD - 1) v = b[n];
    }
    out[idx] = __float2half(v);
}

__global__ __launch_bounds__(256) void prep_eff(
    const float* __restrict__ g_wih, const float* __restrict__ g_bih,
    const float* __restrict__ w2, const float* __restrict__ b2,
    __half* __restrict__ out)
{
    const int li  = blockIdx.y;
    const int idx = blockIdx.x * 256 + threadIdx.x;   // over 128*64
    const int n = idx >> 6, k = idx & 63;
    float v = 0.f;
    if (n < GATES) {
        const float* wrow = g_wih + ((size_t)(li + 1) * GATES + n) * HID;
        if (k < HID) {
            for (int j = 0; j < HID; ++j) v += wrow[j] * w2[((size_t)li * HID + j) * HID + k];
        } else if (k == 63) {
            v = g_bih[(size_t)(li + 1) * GATES + n];
            for (int j = 0; j < HID; ++j) v += wrow[j] * b2[(size_t)li * HID + j];
        }
    }
    out[(size_t)li * 128 * 64 + idx] = __float2half(v);
}

__global__ __launch_bounds__(256) void prep_f16cvt(
    const float* __restrict__ w, _Float16* __restrict__ o, int n)
{
    const int i = blockIdx.x * 256 + threadIdx.x;
    if (i < n) o[i] = (_Float16)w[i];
}

// ---------------- MFMA gate precompute (verified R7/R8) ----------------
template<int MODE>
__global__ __launch_bounds__(256) void precomp_mfma(
    const void* in_, _Float16* xp,
    const _Float16* __restrict__ wihpad,  // [128][KP]
    const _Float16* __restrict__ w1pad,   // [48][64] (MODE 2 only)
    int nrows)
{
    __shared__ _Float16 s_v[4][1024];     // per-wave 2KB swizzled V tile [16][64]
    const int tid  = threadIdx.x;
    const int wid  = tid >> 6, lane = tid & 63;
    const int g    = lane >> 4, r = lane & 15;

    constexpr int KP  = (MODE == 0) ? 32 : 64;
    constexpr int NKS = KP / 32;

    half8 bw[8][NKS];
    #pragma unroll
    for (int t = 0; t < 8; ++t)
        #pragma unroll
        for (int ks = 0; ks < NKS; ++ks)
            bw[t][ks] = *reinterpret_cast<const half8*>(wihpad + (t * 16 + r) * KP + ks * 32 + g * 8);

    half8 b1f[3][2];
    char* myv = nullptr;
    if constexpr (MODE == 2) {
        #pragma unroll
        for (int t = 0; t < 3; ++t)
            #pragma unroll
            for (int ks = 0; ks < 2; ++ks)
                b1f[t][ks] = *reinterpret_cast<const half8*>(w1pad + (t * 16 + r) * 64 + ks * 32 + g * 8);
        myv = (char*)&s_v[wid][0];
        uint4 z; z.x = z.y = z.z = z.w = 0u;
        *reinterpret_cast<uint4*>(myv + lane * 32)      = z;
        *reinterpret_cast<uint4*>(myv + lane * 32 + 16) = z;
        wavesync();
        if (lane < 16)
            *reinterpret_cast<_Float16*>(myv + lane * 128 + (126 ^ ((lane & 7) << 4))) = (_Float16)1.f;
        wavesync();
    }

    const int w0     = blockIdx.x * 4 + wid;
    const int stride = gridDim.x * 64;

    for (int rb = w0 * 16; rb < nrows; rb += stride) {
        half8 a0, a1;
        if constexpr (MODE == 0) {
            const float* xr = (const float*)in_ + (size_t)(rb + r) * 20;
            if (g < 2) {
                const float4 v0 = *reinterpret_cast<const float4*>(xr + g * 8);
                const float4 v1 = *reinterpret_cast<const float4*>(xr + g * 8 + 4);
                a0[0]=(_Float16)v0.x; a0[1]=(_Float16)v0.y; a0[2]=(_Float16)v0.z; a0[3]=(_Float16)v0.w;
                a0[4]=(_Float16)v1.x; a0[5]=(_Float16)v1.y; a0[6]=(_Float16)v1.z; a0[7]=(_Float16)v1.w;
            } else if (g == 2) {
                const float4 v0 = *reinterpret_cast<const float4*>(xr + 16);
                a0[0]=(_Float16)v0.x; a0[1]=(_Float16)v0.y; a0[2]=(_Float16)v0.z; a0[3]=(_Float16)v0.w;
                a0[4]=(_Float16)0.f; a0[5]=(_Float16)0.f; a0[6]=(_Float16)0.f; a0[7]=(_Float16)0.f;
            } else {
                #pragma unroll
                for (int j = 0; j < 8; ++j) a0[j] = (_Float16)0.f;
                a0[7] = (_Float16)1.f;    // bias slot k=31
            }
        } else {
            const _Float16* hr = (const _Float16*)in_ + (size_t)(rb + r) * GATES;
            a0 = *reinterpret_cast<const half8*>(hr + g * 8);          // k 0..31
            if (g == 0) {
                a1 = *reinterpret_cast<const half8*>(hr + 32);         // k 32..39
            } else {
                #pragma unroll
                for (int j = 0; j < 8; ++j) a1[j] = (_Float16)0.f;
                if (g == 3) a1[7] = (_Float16)1.f;                     // bias slot k=63
            }
        }

        if constexpr (MODE == 2) {
            #pragma unroll
            for (int t = 0; t < 3; ++t) {
                f32x4 acc = {0.f, 0.f, 0.f, 0.f};
                acc = __builtin_amdgcn_mfma_f32_16x16x32_f16(a0, b1f[t][0], acc, 0, 0, 0);
                acc = __builtin_amdgcn_mfma_f32_16x16x32_f16(a1, b1f[t][1], acc, 0, 0, 0);
                const int n2 = (t * 16 + r) * 2;                       // byte col
                #pragma unroll
                for (int reg = 0; reg < 4; ++reg) {
                    const int m = g * 4 + reg;
                    float v = acc[reg];
                    v = v > 0.f ? v : 0.01f * v;
                    *reinterpret_cast<_Float16*>(myv + m * 128 + (n2 ^ ((m & 7) << 4))) = (_Float16)v;
                }
            }
            wavesync();
            const int sw = (r & 7) << 4;
            a0 = *reinterpret_cast<const half8*>(myv + r * 128 + ((g * 16) ^ sw));
            a1 = *reinterpret_cast<const half8*>(myv + r * 128 + ((64 + g * 16) ^ sw));
        }

        #pragma unroll
        for (int t = 0; t < 8; ++t) {
            f32x4 acc = {0.f, 0.f, 0.f, 0.f};
            acc = __builtin_amdgcn_mfma_f32_16x16x32_f16(a0, bw[t][0], acc, 0, 0, 0);
            if constexpr (NKS == 2)
                acc = __builtin_amdgcn_mfma_f32_16x16x32_f16(a1, bw[t][1], acc, 0, 0, 0);
            const int n = t * 16 + r;
            if (n < GATES) {
                #pragma unroll
                for (int reg = 0; reg < 4; ++reg) {
                    const int m = g * 4 + reg;
                    xp[(size_t)(rb + m) * GATES + n] = (_Float16)acc[reg];
                }
            }
        }
    }
}

// ---------------- recurrence: LDS-resident weights, 2 elements per wave ----------------
// whh staged once into LDS (f16 [120][40]). Per step: 10 weight b128 reads shared
// by BOTH elements, 80 fdot2, bperm-z, lane-local activation. Weights physically
// on-chip: the compiler cannot turn them into global reloads (R8/R9/R10 failure
// mode), and the in-loop wavesync memory clobber stops hoisting.
__global__ __launch_bounds__(64) void gru_rec2(
    __half* xp,                         // [CB, T, 120], h written into [t][0:40]
    const _Float16* __restrict__ whh16, // [120][40] f16
    const float* __restrict__ bhh)      // [120]
{
    __shared__ __align__(16) _Float16 s_w[GATES * HID];  // 9600 B
    __shared__ __align__(16) _Float16 s_h[2][64];

    const int lane = threadIdx.x;
    const int e0   = blockIdx.x * 2;

    for (int idx = lane; idx < (GATES * HID) / 8; idx += 64)
        reinterpret_cast<uint4*>(s_w)[idx] = reinterpret_cast<const uint4*>(whh16)[idx];

    const int gA = lane;
    const int gB = (lane < 40) ? (80 + lane) : ((lane < 56) ? (24 + lane) : lane);
    const float bhA = bhh[gA], bhB = bhh[gB];

    __half* xpb0 = xp + (size_t)e0 * T_STEPS * GATES;
    __half* xpb1 = xpb0 + (size_t)T_STEPS * GATES;

    float h0reg = 0.f, h1reg = 0.f;
    s_h[0][lane] = (_Float16)0.f;
    s_h[1][lane] = (_Float16)0.f;

    // 2-deep xp prefetch per element (loads stay in flight across wavesync)
    __half a00 = xpb0[gA],         c00 = xpb0[gB];
    __half a01 = xpb0[GATES + gA], c01 = xpb0[GATES + gB];
    __half a10 = xpb1[gA],         c10 = xpb1[gB];
    __half a11 = xpb1[GATES + gA], c11 = xpb1[GATES + gB];
    wavesync();   // staging + s_h init complete

    const _Float16* wrA = s_w + gA * HID;
    const _Float16* wrB = s_w + gB * HID;

    for (int t = 0; t < T_STEPS; ++t) {
        __half a02 = a00, c02 = c00, a12 = a10, c12 = c10;
        if (t + 2 < T_STEPS) {
            a02 = xpb0[(size_t)(t + 2) * GATES + gA];
            c02 = xpb0[(size_t)(t + 2) * GATES + gB];
            a12 = xpb1[(size_t)(t + 2) * GATES + gA];
            c12 = xpb1[(size_t)(t + 2) * GATES + gB];
        }

        // dots: weights read once from LDS, used for both elements
        float A0[4] = {0,0,0,0}, B0[4] = {0,0,0,0};
        float A1[4] = {0,0,0,0}, B1[4] = {0,0,0,0};
        #pragma unroll
        for (int k = 0; k < 5; ++k) {
            const half8 wa = *reinterpret_cast<const half8*>(wrA + k * 8);
            const half8 wb = *reinterpret_cast<const half8*>(wrB + k * 8);
            const half8 p0 = *reinterpret_cast<const half8*>(&s_h[0][k * 8]);
            const half8 p1 = *reinterpret_cast<const half8*>(&s_h[1][k * 8]);
            A0[0] = fdot2(ext2<0>(p0), ext2<0>(wa), A0[0]);
            B0[0] = fdot2(ext2<0>(p0), ext2<0>(wb), B0[0]);
            A1[0] = fdot2(ext2<0>(p1), ext2<0>(wa), A1[0]);
            B1[0] = fdot2(ext2<0>(p1), ext2<0>(wb), B1[0]);
            A0[1] = fdot2(ext2<1>(p0), ext2<1>(wa), A0[1]);
            B0[1] = fdot2(ext2<1>(p0), ext2<1>(wb), B0[1]);
            A1[1] = fdot2(ext2<1>(p1), ext2<1>(wa), A1[1]);
            B1[1] = fdot2(ext2<1>(p1), ext2<1>(wb), B1[1]);
            A0[2] = fdot2(ext2<2>(p0), ext2<2>(wa), A0[2]);
            B0[2] = fdot2(ext2<2>(p0), ext2<2>(wb), B0[2]);
            A1[2] = fdot2(ext2<2>(p1), ext2<2>(wa), A1[2]);
            B1[2] = fdot2(ext2<2>(p1), ext2<2>(wb), B1[2]);
            A0[3] = fdot2(ext2<3>(p0), ext2<3>(wa), A0[3]);
            B0[3] = fdot2(ext2<3>(p0), ext2<3>(wb), B0[3]);
            A1[3] = fdot2(ext2<3>(p1), ext2<3>(wa), A1[3]);
            B1[3] = fdot2(ext2<3>(p1), ext2<3>(wb), B1[3]);
        }
        const float shA0 = bhA + ((A0[0] + A0[2]) + (A0[1] + A0[3]));
        const float shB0 = bhB + ((B0[0] + B0[2]) + (B0[1] + B0[3]));
        const float shA1 = bhA + ((A1[0] + A1[2]) + (A1[1] + A1[3]));
        const float shB1 = bhB + ((B1[0] + B1[2]) + (B1[1] + B1[3]));
        const float xA0 = __half2float(a00), xB0 = __half2float(c00);
        const float xA1 = __half2float(a10), xB1 = __half2float(c10);
        const float sumA0 = xA0 + shA0, sumB0 = xB0 + shB0;
        const float sumA1 = xA1 + shA1, sumB1 = xB1 + shB1;
        // z_l: lane 40+l (sumA) for l<24, lane 16+l (sumB) for l>=24. All lanes execute.
        const float zA0 = bperm(40 + lane, sumA0), zB0 = bperm(16 + lane, sumB0);
        const float zA1 = bperm(40 + lane, sumA1), zB1 = bperm(16 + lane, sumB1);

        if (lane < HID) {
            {
                const float rr  = sigm(sumA0);
                const float z   = sigm((lane < 24) ? zA0 : zB0);
                const float pre = xB0 + rr * shB0;    // x_n + r*h_n (biases included)
                const float ex  = __expf(-2.f * pre);
                const float nn  = (1.f - ex) / (1.f + ex);
                h0reg = (1.f - z) * nn + z * h0reg;
                s_h[0][lane] = (_Float16)h0reg;
                xpb0[(size_t)t * GATES + lane] = __float2half(h0reg);
            }
            {
                const float rr  = sigm(sumA1);
                const float z   = sigm((lane < 24) ? zA1 : zB1);
                const float pre = xB1 + rr * shB1;
                const float ex  = __expf(-2.f * pre);
                const float nn  = (1.f - ex) / (1.f + ex);
                h1reg = (1.f - z) * nn + z * h1reg;
                s_h[1][lane] = (_Float16)h1reg;
                xpb1[(size_t)t * GATES + lane] = __float2half(h1reg);
            }
        }
        a00 = a01; c00 = c01; a01 = a02; c01 = c02;
        a10 = a11; c10 = c11; a11 = a12; c11 = c12;
        wavesync();   // s_h staged for next step (also pins weight reads in-loop)
    }
}

// ---------------- head (unchanged) ----------------
__global__ __launch_bounds__(256) void final_head(
    const __half* __restrict__ hbase,  // xpbuf + (T-1)*GATES
    float* __restrict__ outp,          // [CB]
    const float* __restrict__ w1, const float* __restrict__ b1,
    const float* __restrict__ wl, const float* __restrict__ bl, int n)
{
    __shared__ float s_w1[HID][HID + 1];
    __shared__ float s_b1[HID];
    __shared__ float s_wl[HID];
    for (int i = threadIdx.x; i < HID * HID; i += 256) s_w1[i / HID][i % HID] = w1[i];
    if (threadIdx.x < HID) { s_b1[threadIdx.x] = b1[threadIdx.x]; s_wl[threadIdx.x] = wl[threadIdx.x]; }
    __syncthreads();
    const int e = blockIdx.x * 256 + threadIdx.x;
    if (e >= n) return;

    alignas(16) __half hx[HID];
    const uint4* hr = reinterpret_cast<const uint4*>(hbase + (size_t)e * T_STEPS * GATES);
    #pragma unroll
    for (int q = 0; q < HID / 8; ++q) reinterpret_cast<uint4*>(hx)[q] = hr[q];
    float h[HID];
    #pragma unroll
    for (int k = 0; k < HID; ++k) h[k] = __half2float(hx[k]);

    float acc = bl[0];
    #pragma unroll
    for (int u = 0; u < HID; ++u) {
        float a = s_b1[u];
        #pragma unroll
        for (int d = 0; d < HID; ++d) a += s_w1[u][d] * h[d];
        a = a > 0.f ? a : 0.01f * a;
        acc += a * s_wl[u];
    }
    outp[e] = 1.f / (1.f + __expf(-acc));
}

extern "C" void kernel_launch(void* const* d_in, const int* in_sizes, int n_in,
                              void* d_out, int out_size, void* d_ws, size_t ws_size,
                              hipStream_t stream)
{
    const float* x      = (const float*)d_in[0];
    const float* g0_wih = (const float*)d_in[1];
    const float* g0_whh = (const float*)d_in[2];
    const float* g0_bih = (const float*)d_in[3];
    const float* g0_bhh = (const float*)d_in[4];
    const float* g_wih  = (const float*)d_in[5];   // [4,120,40]
    const float* g_whh  = (const float*)d_in[6];   // [4,120,40]
    const float* g_bih  = (const float*)d_in[7];   // [4,120]
    const float* g_bhh  = (const float*)d_in[8];   // [4,120]
    const float* mlp_w1 = (const float*)d_in[9];   // [4,40,40]
    const float* mlp_b1 = (const float*)d_in[10];  // [4,40]
    const float* mlp_w2 = (const float*)d_in[11];  // [3,40,40]
    const float* mlp_b2 = (const float*)d_in[12];  // [3,40]
    const float* w_last = (const float*)d_in[13];  // [1,40]
    const float* b_last = (const float*)d_in[14];  // [1]

    const int B = in_sizes[0] / (T_STEPS * 20);
    float* out = (float*)d_out;

    // ws (halfs): [w1pad 3*3072][effpad 3*8192][g0pad 4096][g1pad 8192][whh16 5*4800] then xp
    __half* wsz    = (__half*)d_ws;
    __half* w1pad  = wsz;                       // 9216
    __half* effpad = wsz + 3 * 3072;            // 24576
    __half* g0pad  = wsz + 9216 + 3 * 8192;     // 4096
    __half* g1pad  = g0pad + 4096;              // 8192
    _Float16* whh16 = (_Float16*)(wsz + 46080); // 24000
    _Float16* xpbuf = (_Float16*)(wsz + 70080); // 140160 B of weights, 16B aligned
    const size_t ws_rem = ws_size - 70080 * sizeof(__half);

    for (int li = 0; li < 3; ++li)
        prep_pad<<<dim3(12), dim3(256), 0, stream>>>(
            mlp_w1 + li * 1600, mlp_b1 + li * 40, w1pad + li * 3072, 40, 40, 64);
    prep_pad<<<dim3(16), dim3(256), 0, stream>>>(g0_wih, g0_bih, g0pad, 120, 20, 32);
    prep_pad<<<dim3(32), dim3(256), 0, stream>>>(g_wih, g_bih, g1pad, 120, 40, 64);
    prep_eff<<<dim3(32, 3), dim3(256), 0, stream>>>(g_wih, g_bih, mlp_w2, mlp_b2, effpad);
    prep_f16cvt<<<dim3(19), dim3(256), 0, stream>>>(g0_whh, whh16, 4800);
    prep_f16cvt<<<dim3(75), dim3(256), 0, stream>>>(g_whh, whh16 + 4800, 19200);

    const size_t per_e = (size_t)T_STEPS * GATES * sizeof(__half);  // 240 B/row
    int CB = B;
    while ((size_t)CB * per_e > ws_rem && CB > 64) CB >>= 1;

    for (int c = 0; c < B; c += CB) {
        const int  nrows = CB * T_STEPS;
        const dim3 pgrd(nrows / 512), pblk(256);
        const dim3 rgrd(CB / 2), rblk(64);
        const float* xc = x + (size_t)c * T_STEPS * 20;

        precomp_mfma<0><<<pgrd, pblk, 0, stream>>>(
            xc, xpbuf, (const _Float16*)g0pad, nullptr, nrows);
        gru_rec2<<<rgrd, rblk, 0, stream>>>((__half*)xpbuf, whh16, g0_bhh);

        precomp_mfma<1><<<pgrd, pblk, 0, stream>>>(
            xpbuf, xpbuf, (const _Float16*)g1pad, nullptr, nrows);
        gru_rec2<<<rgrd, rblk, 0, stream>>>((__half*)xpbuf, whh16 + 4800, g_bhh + 0 * 120);

        for (int li = 0; li < 3; ++li) {
            precomp_mfma<2><<<pgrd, pblk, 0, stream>>>(
                xpbuf, xpbuf, (const _Float16*)(effpad + li * 8192),
                (const _Float16*)(w1pad + li * 3072), nrows);
            gru_rec2<<<rgrd, rblk, 0, stream>>>(
                (__half*)xpbuf, whh16 + 4800 + (li + 1) * 4800, g_bhh + (li + 1) * 120);
        }

        final_head<<<dim3((CB + 255) / 256), dim3(256), 0, stream>>>(
            (const __half*)(xpbuf + (size_t)(T_STEPS - 1) * GATES), out + c,
            mlp_w1 + 3 * 1600, mlp_b1 + 3 * 40, w_last, b_last, CB);
    }
}

// Round 14
// 2492.434 us; speedup vs baseline: 1.9528x; 1.2325x over previous
//
#include <hip/hip_runtime.h>
#include <hip/hip_fp16.h>
#include <cstdint>
#include <cstddef>

#define T_STEPS 512
#define HID 40
#define GATES 120

typedef _Float16 half8 __attribute__((ext_vector_type(8)));
typedef _Float16 fp16x2 __attribute__((ext_vector_type(2)));
typedef float f32x4 __attribute__((ext_vector_type(4)));

// Single-wave-block "barrier": lanes lockstep; only LDS completion ordering needed.
__device__ __forceinline__ void wavesync() { asm volatile("s_waitcnt lgkmcnt(0)" ::: "memory"); }
__device__ __forceinline__ float bperm(int srclane, float v) {
    return __int_as_float(__builtin_amdgcn_ds_bpermute(srclane << 2, __float_as_int(v)));
}
__device__ __forceinline__ float sigm(float x) { return 1.f / (1.f + __expf(-x)); }

// parse-time-constant fp16x2 extraction from a half8
template<int J>
__device__ __forceinline__ fp16x2 ext2(half8 v) {
    return __builtin_shufflevector(v, v, 2 * J, 2 * J + 1);
}

#if __has_builtin(__builtin_amdgcn_fdot2)
__device__ __forceinline__ float fdot2(fp16x2 a, fp16x2 b, float c) {
    return __builtin_amdgcn_fdot2(a, b, c, false);
}
#else
__device__ __forceinline__ float fdot2(fp16x2 a, fp16x2 b, float c) {
    return c + (float)a[0] * (float)b[0] + (float)a[1] * (float)b[1];
}
#endif

// ---------------- weight prep (run once, tiny) ----------------
__global__ __launch_bounds__(256) void prep_pad(
    const float* __restrict__ w, const float* __restrict__ b,
    __half* __restrict__ out, int N, int K, int KPAD)
{
    const int idx = blockIdx.x * 256 + threadIdx.x;
    const int n = idx / KPAD, k = idx - n * KPAD;
    float v = 0.f;
    if (n < N) {
        if (k < K) v = w[n * K + k];
        else if (k == KPAD - 1) v = b[n];
    }
    out[idx] = __float2half(v);
}

__global__ __launch_bounds__(256) void prep_eff(
    const float* __restrict__ g_wih, const float* __restrict__ g_bih,
    const float* __restrict__ w2, const float* __restrict__ b2,
    __half* __restrict__ out)
{
    const int li  = blockIdx.y;
    const int idx = blockIdx.x * 256 + threadIdx.x;   // over 128*64
    const int n = idx >> 6, k = idx & 63;
    float v = 0.f;
    if (n < GATES) {
        const float* wrow = g_wih + ((size_t)(li + 1) * GATES + n) * HID;
        if (k < HID) {
            for (int j = 0; j < HID; ++j) v += wrow[j] * w2[((size_t)li * HID + j) * HID + k];
        } else if (k == 63) {
            v = g_bih[(size_t)(li + 1) * GATES + n];
            for (int j = 0; j < HID; ++j) v += wrow[j] * b2[(size_t)li * HID + j];
        }
    }
    out[(size_t)li * 128 * 64 + idx] = __float2half(v);
}

__global__ __launch_bounds__(256) void prep_f16cvt(
    const float* __restrict__ w, _Float16* __restrict__ o, int n)
{
    const int i = blockIdx.x * 256 + threadIdx.x;
    if (i < n) o[i] = (_Float16)w[i];
}

// ---------------- MFMA gate precompute (verified R7/R8/R13) ----------------
template<int MODE>
__global__ __launch_bounds__(256) void precomp_mfma(
    const void* in_, _Float16* xp,
    const _Float16* __restrict__ wihpad,  // [128][KP]
    const _Float16* __restrict__ w1pad,   // [48][64] (MODE 2 only)
    int nrows)
{
    __shared__ _Float16 s_v[4][1024];     // per-wave 2KB swizzled V tile [16][64]
    const int tid  = threadIdx.x;
    const int wid  = tid >> 6, lane = tid & 63;
    const int g    = lane >> 4, r = lane & 15;

    constexpr int KP  = (MODE == 0) ? 32 : 64;
    constexpr int NKS = KP / 32;

    half8 bw[8][NKS];
    #pragma unroll
    for (int t = 0; t < 8; ++t)
        #pragma unroll
        for (int ks = 0; ks < NKS; ++ks)
            bw[t][ks] = *reinterpret_cast<const half8*>(wihpad + (t * 16 + r) * KP + ks * 32 + g * 8);

    half8 b1f[3][2];
    char* myv = nullptr;
    if constexpr (MODE == 2) {
        #pragma unroll
        for (int t = 0; t < 3; ++t)
            #pragma unroll
            for (int ks = 0; ks < 2; ++ks)
                b1f[t][ks] = *reinterpret_cast<const half8*>(w1pad + (t * 16 + r) * 64 + ks * 32 + g * 8);
        myv = (char*)&s_v[wid][0];
        uint4 z; z.x = z.y = z.z = z.w = 0u;
        *reinterpret_cast<uint4*>(myv + lane * 32)      = z;
        *reinterpret_cast<uint4*>(myv + lane * 32 + 16) = z;
        wavesync();
        if (lane < 16)
            *reinterpret_cast<_Float16*>(myv + lane * 128 + (126 ^ ((lane & 7) << 4))) = (_Float16)1.f;
        wavesync();
    }

    const int w0     = blockIdx.x * 4 + wid;
    const int stride = gridDim.x * 64;

    for (int rb = w0 * 16; rb < nrows; rb += stride) {
        half8 a0, a1;
        if constexpr (MODE == 0) {
            const float* xr = (const float*)in_ + (size_t)(rb + r) * 20;
            if (g < 2) {
                const float4 v0 = *reinterpret_cast<const float4*>(xr + g * 8);
                const float4 v1 = *reinterpret_cast<const float4*>(xr + g * 8 + 4);
                a0[0]=(_Float16)v0.x; a0[1]=(_Float16)v0.y; a0[2]=(_Float16)v0.z; a0[3]=(_Float16)v0.w;
                a0[4]=(_Float16)v1.x; a0[5]=(_Float16)v1.y; a0[6]=(_Float16)v1.z; a0[7]=(_Float16)v1.w;
            } else if (g == 2) {
                const float4 v0 = *reinterpret_cast<const float4*>(xr + 16);
                a0[0]=(_Float16)v0.x; a0[1]=(_Float16)v0.y; a0[2]=(_Float16)v0.z; a0[3]=(_Float16)v0.w;
                a0[4]=(_Float16)0.f; a0[5]=(_Float16)0.f; a0[6]=(_Float16)0.f; a0[7]=(_Float16)0.f;
            } else {
                #pragma unroll
                for (int j = 0; j < 8; ++j) a0[j] = (_Float16)0.f;
                a0[7] = (_Float16)1.f;    // bias slot k=31
            }
        } else {
            const _Float16* hr = (const _Float16*)in_ + (size_t)(rb + r) * GATES;
            a0 = *reinterpret_cast<const half8*>(hr + g * 8);          // k 0..31
            if (g == 0) {
                a1 = *reinterpret_cast<const half8*>(hr + 32);         // k 32..39
            } else {
                #pragma unroll
                for (int j = 0; j < 8; ++j) a1[j] = (_Float16)0.f;
                if (g == 3) a1[7] = (_Float16)1.f;                     // bias slot k=63
            }
        }

        if constexpr (MODE == 2) {
            #pragma unroll
            for (int t = 0; t < 3; ++t) {
                f32x4 acc = {0.f, 0.f, 0.f, 0.f};
                acc = __builtin_amdgcn_mfma_f32_16x16x32_f16(a0, b1f[t][0], acc, 0, 0, 0);
                acc = __builtin_amdgcn_mfma_f32_16x16x32_f16(a1, b1f[t][1], acc, 0, 0, 0);
                const int n2 = (t * 16 + r) * 2;                       // byte col
                #pragma unroll
                for (int reg = 0; reg < 4; ++reg) {
                    const int m = g * 4 + reg;
                    float v = acc[reg];
                    v = v > 0.f ? v : 0.01f * v;
                    *reinterpret_cast<_Float16*>(myv + m * 128 + (n2 ^ ((m & 7) << 4))) = (_Float16)v;
                }
            }
            wavesync();
            const int sw = (r & 7) << 4;
            a0 = *reinterpret_cast<const half8*>(myv + r * 128 + ((g * 16) ^ sw));
            a1 = *reinterpret_cast<const half8*>(myv + r * 128 + ((64 + g * 16) ^ sw));
        }

        #pragma unroll
        for (int t = 0; t < 8; ++t) {
            f32x4 acc = {0.f, 0.f, 0.f, 0.f};
            acc = __builtin_amdgcn_mfma_f32_16x16x32_f16(a0, bw[t][0], acc, 0, 0, 0);
            if constexpr (NKS == 2)
                acc = __builtin_amdgcn_mfma_f32_16x16x32_f16(a1, bw[t][1], acc, 0, 0, 0);
            const int n = t * 16 + r;
            if (n < GATES) {
                #pragma unroll
                for (int reg = 0; reg < 4; ++reg) {
                    const int m = g * 4 + reg;
                    xp[(size_t)(rb + m) * GATES + n] = (_Float16)acc[reg];
                }
            }
        }
    }
}

// ---------------- recurrence: LDS weights, 1 element/wave, 2048 blocks ----------------
// R13 proved LDS weight reads at stride-80B rows are conflict-free and cheaper than
// the compiler's per-step global reloads (R8-R10); R13 also proved E=2 kills
// occupancy. This kernel = R13's weight scheme at R7's occupancy (8 waves/CU).
// Per step: 5 weight b128 + 1 h b128 (uniform) reads, 40 fdot2, bperm-z, activation.
__global__ __launch_bounds__(64) void gru_recL(
    __half* __restrict__ xp,            // [CB, T, 120], h written into [t][0:40]
    const _Float16* __restrict__ whh16, // [120][40] f16
    const float* __restrict__ bhh)      // [120]
{
    __shared__ __align__(16) _Float16 s_w[GATES * HID];  // 9600 B
    __shared__ __align__(16) _Float16 s_h[64];

    const int lane = threadIdx.x;
    const int e    = blockIdx.x;

    for (int idx = lane; idx < (GATES * HID) / 8; idx += 64)
        reinterpret_cast<uint4*>(s_w)[idx] = reinterpret_cast<const uint4*>(whh16)[idx];

    const int gA = lane;
    const int gB = (lane < 40) ? (80 + lane) : ((lane < 56) ? (24 + lane) : lane);
    const float bhA = bhh[gA], bhB = bhh[gB];

    __half* xpb = xp + (size_t)e * T_STEPS * GATES;

    float hreg = 0.f;
    s_h[lane] = (_Float16)0.f;

    // 3-deep xp prefetch (loads stay in flight across wavesync: vmcnt untouched)
    __half a0 = xpb[gA],             c0 = xpb[gB];
    __half a1 = xpb[GATES + gA],     c1 = xpb[GATES + gB];
    __half a2 = xpb[2 * GATES + gA], c2 = xpb[2 * GATES + gB];
    wavesync();   // staging + s_h init complete

    const _Float16* wrA = s_w + gA * HID;
    const _Float16* wrB = s_w + gB * HID;

    for (int t = 0; t < T_STEPS; ++t) {
        __half a3 = a0, c3 = c0;
        if (t + 3 < T_STEPS) {
            a3 = xpb[(size_t)(t + 3) * GATES + gA];
            c3 = xpb[(size_t)(t + 3) * GATES + gB];
        }

        float A0[4] = {0,0,0,0}, B0[4] = {0,0,0,0};
        #pragma unroll
        for (int k = 0; k < 5; ++k) {
            const half8 wa = *reinterpret_cast<const half8*>(wrA + k * 8);
            const half8 wb = *reinterpret_cast<const half8*>(wrB + k * 8);
            const half8 p  = *reinterpret_cast<const half8*>(&s_h[k * 8]);
            A0[0] = fdot2(ext2<0>(p), ext2<0>(wa), A0[0]);
            B0[0] = fdot2(ext2<0>(p), ext2<0>(wb), B0[0]);
            A0[1] = fdot2(ext2<1>(p), ext2<1>(wa), A0[1]);
            B0[1] = fdot2(ext2<1>(p), ext2<1>(wb), B0[1]);
            A0[2] = fdot2(ext2<2>(p), ext2<2>(wa), A0[2]);
            B0[2] = fdot2(ext2<2>(p), ext2<2>(wb), B0[2]);
            A0[3] = fdot2(ext2<3>(p), ext2<3>(wa), A0[3]);
            B0[3] = fdot2(ext2<3>(p), ext2<3>(wb), B0[3]);
        }
        const float shA = bhA + ((A0[0] + A0[2]) + (A0[1] + A0[3]));
        const float shB = bhB + ((B0[0] + B0[2]) + (B0[1] + B0[3]));
        const float xA  = __half2float(a0);
        const float xB  = __half2float(c0);
        const float sumA = xA + shA;
        const float sumB = xB + shB;
        // z_l: lane 40+l (sumA) for l<24, lane 16+l (sumB) for l>=24. All lanes execute.
        const float zA = bperm(40 + lane, sumA);
        const float zB = bperm(16 + lane, sumB);

        if (lane < HID) {
            const float rr  = sigm(sumA);
            const float z   = sigm((lane < 24) ? zA : zB);
            const float pre = xB + rr * shB;          // x_n + r*h_n (biases included)
            const float ex  = __expf(-2.f * pre);
            const float nn  = (1.f - ex) / (1.f + ex);
            hreg = (1.f - z) * nn + z * hreg;
            s_h[lane] = (_Float16)hreg;
            xpb[(size_t)t * GATES + lane] = __float2half(hreg);
        }
        a0 = a1; c0 = c1; a1 = a2; c1 = c2; a2 = a3; c2 = c3;
        wavesync();   // s_h staged for next step
    }
}

// ---------------- head (unchanged) ----------------
__global__ __launch_bounds__(256) void final_head(
    const __half* __restrict__ hbase,  // xpbuf + (T-1)*GATES
    float* __restrict__ outp,          // [CB]
    const float* __restrict__ w1, const float* __restrict__ b1,
    const float* __restrict__ wl, const float* __restrict__ bl, int n)
{
    __shared__ float s_w1[HID][HID + 1];
    __shared__ float s_b1[HID];
    __shared__ float s_wl[HID];
    for (int i = threadIdx.x; i < HID * HID; i += 256) s_w1[i / HID][i % HID] = w1[i];
    if (threadIdx.x < HID) { s_b1[threadIdx.x] = b1[threadIdx.x]; s_wl[threadIdx.x] = wl[threadIdx.x]; }
    __syncthreads();
    const int e = blockIdx.x * 256 + threadIdx.x;
    if (e >= n) return;

    alignas(16) __half hx[HID];
    const uint4* hr = reinterpret_cast<const uint4*>(hbase + (size_t)e * T_STEPS * GATES);
    #pragma unroll
    for (int q = 0; q < HID / 8; ++q) reinterpret_cast<uint4*>(hx)[q] = hr[q];
    float h[HID];
    #pragma unroll
    for (int k = 0; k < HID; ++k) h[k] = __half2float(hx[k]);

    float acc = bl[0];
    #pragma unroll
    for (int u = 0; u < HID; ++u) {
        float a = s_b1[u];
        #pragma unroll
        for (int d = 0; d < HID; ++d) a += s_w1[u][d] * h[d];
        a = a > 0.f ? a : 0.01f * a;
        acc += a * s_wl[u];
    }
    outp[e] = 1.f / (1.f + __expf(-acc));
}

extern "C" void kernel_launch(void* const* d_in, const int* in_sizes, int n_in,
                              void* d_out, int out_size, void* d_ws, size_t ws_size,
                              hipStream_t stream)
{
    const float* x      = (const float*)d_in[0];
    const float* g0_wih = (const float*)d_in[1];
    const float* g0_whh = (const float*)d_in[2];
    const float* g0_bih = (const float*)d_in[3];
    const float* g0_bhh = (const float*)d_in[4];
    const float* g_wih  = (const float*)d_in[5];   // [4,120,40]
    const float* g_whh  = (const float*)d_in[6];   // [4,120,40]
    const float* g_bih  = (const float*)d_in[7];   // [4,120]
    const float* g_bhh  = (const float*)d_in[8];   // [4,120]
    const float* mlp_w1 = (const float*)d_in[9];   // [4,40,40]
    const float* mlp_b1 = (const float*)d_in[10];  // [4,40]
    const float* mlp_w2 = (const float*)d_in[11];  // [3,40,40]
    const float* mlp_b2 = (const float*)d_in[12];  // [3,40]
    const float* w_last = (const float*)d_in[13];  // [1,40]
    const float* b_last = (const float*)d_in[14];  // [1]

    const int B = in_sizes[0] / (T_STEPS * 20);
    float* out = (float*)d_out;

    // ws (halfs): [w1pad 3*3072][effpad 3*8192][g0pad 4096][g1pad 8192][whh16 5*4800] then xp
    __half* wsz    = (__half*)d_ws;
    __half* w1pad  = wsz;                       // 9216
    __half* effpad = wsz + 3 * 3072;            // 24576
    __half* g0pad  = wsz + 9216 + 3 * 8192;     // 4096
    __half* g1pad  = g0pad + 4096;              // 8192
    _Float16* whh16 = (_Float16*)(wsz + 46080); // 24000
    _Float16* xpbuf = (_Float16*)(wsz + 70080); // 140160 B of weights, 16B aligned
    const size_t ws_rem = ws_size - 70080 * sizeof(__half);

    for (int li = 0; li < 3; ++li)
        prep_pad<<<dim3(12), dim3(256), 0, stream>>>(
            mlp_w1 + li * 1600, mlp_b1 + li * 40, w1pad + li * 3072, 40, 40, 64);
    prep_pad<<<dim3(16), dim3(256), 0, stream>>>(g0_wih, g0_bih, g0pad, 120, 20, 32);
    prep_pad<<<dim3(32), dim3(256), 0, stream>>>(g_wih, g_bih, g1pad, 120, 40, 64);
    prep_eff<<<dim3(32, 3), dim3(256), 0, stream>>>(g_wih, g_bih, mlp_w2, mlp_b2, effpad);
    prep_f16cvt<<<dim3(19), dim3(256), 0, stream>>>(g0_whh, whh16, 4800);
    prep_f16cvt<<<dim3(75), dim3(256), 0, stream>>>(g_whh, whh16 + 4800, 19200);

    const size_t per_e = (size_t)T_STEPS * GATES * sizeof(__half);  // 240 B/row
    int CB = B;
    while ((size_t)CB * per_e > ws_rem && CB > 64) CB >>= 1;

    for (int c = 0; c < B; c += CB) {
        const int  nrows = CB * T_STEPS;
        const dim3 pgrd(nrows / 512), pblk(256);
        const dim3 rgrd(CB), rblk(64);
        const float* xc = x + (size_t)c * T_STEPS * 20;

        precomp_mfma<0><<<pgrd, pblk, 0, stream>>>(
            xc, xpbuf, (const _Float16*)g0pad, nullptr, nrows);
        gru_recL<<<rgrd, rblk, 0, stream>>>((__half*)xpbuf, whh16, g0_bhh);

        precomp_mfma<1><<<pgrd, pblk, 0, stream>>>(
            xpbuf, xpbuf, (const _Float16*)g1pad, nullptr, nrows);
        gru_recL<<<rgrd, rblk, 0, stream>>>((__half*)xpbuf, whh16 + 4800, g_bhh + 0 * 120);

        for (int li = 0; li < 3; ++li) {
            precomp_mfma<2><<<pgrd, pblk, 0, stream>>>(
                xpbuf, xpbuf, (const _Float16*)(effpad + li * 8192),
                (const _Float16*)(w1pad + li * 3072), nrows);
            gru_recL<<<rgrd, rblk, 0, stream>>>(
                (__half*)xpbuf, whh16 + 4800 + (li + 1) * 4800, g_bhh + (li + 1) * 120);
        }

        final_head<<<dim3((CB + 255) / 256), dim3(256), 0, stream>>>(
            (const __half*)(xpbuf + (size_t)(T_STEPS - 1) * GATES), out + c,
            mlp_w1 + 3 * 1600, mlp_b1 + 3 * 40, w_last, b_last, CB);
    }
}

// Round 15
// 2024.852 us; speedup vs baseline: 2.4037x; 1.2309x over previous
//
#include <hip/hip_runtime.h>
#include <hip/hip_fp16.h>
#include <cstdint>
#include <cstddef>

#define T_STEPS 512
#define ROWSP   516          // padded rows per element (3-deep unconditional prefetch)
#define HID 40
#define GATES 120

typedef _Float16 half8 __attribute__((ext_vector_type(8)));
typedef _Float16 fp16x2 __attribute__((ext_vector_type(2)));
typedef float f32x4 __attribute__((ext_vector_type(4)));

__device__ __forceinline__ void wavesync() { asm volatile("s_waitcnt lgkmcnt(0)" ::: "memory"); }
__device__ __forceinline__ float bperm(int srclane, float v) {
    return __int_as_float(__builtin_amdgcn_ds_bpermute(srclane << 2, __float_as_int(v)));
}
__device__ __forceinline__ float sigm(float x) { return 1.f / (1.f + __expf(-x)); }

template<int J>
__device__ __forceinline__ fp16x2 ext2(half8 v) {
    return __builtin_shufflevector(v, v, 2 * J, 2 * J + 1);
}

#if __has_builtin(__builtin_amdgcn_fdot2)
__device__ __forceinline__ float fdot2(fp16x2 a, fp16x2 b, float c) {
    return __builtin_amdgcn_fdot2(a, b, c, false);
}
#else
__device__ __forceinline__ float fdot2(fp16x2 a, fp16x2 b, float c) {
    return c + (float)a[0] * (float)b[0] + (float)a[1] * (float)b[1];
}
#endif

// padded-row byte mapping: row i (linear e*512+t) lives at (e*516+t)*GATES
__device__ __forceinline__ size_t rowoff(int row) {
    return ((size_t)(row >> 9) * ROWSP + (row & 511)) * GATES;
}

// ---------------- weight prep (run once, tiny) ----------------
__global__ __launch_bounds__(256) void prep_pad(
    const float* __restrict__ w, const float* __restrict__ b,
    __half* __restrict__ out, int N, int K, int KPAD)
{
    const int idx = blockIdx.x * 256 + threadIdx.x;
    const int n = idx / KPAD, k = idx - n * KPAD;
    float v = 0.f;
    if (n < N) {
        if (k < K) v = w[n * K + k];
        else if (k == KPAD - 1) v = b[n];
    }
    out[idx] = __float2half(v);
}

__global__ __launch_bounds__(256) void prep_eff(
    const float* __restrict__ g_wih, const float* __restrict__ g_bih,
    const float* __restrict__ w2, const float* __restrict__ b2,
    __half* __restrict__ out)
{
    const int li  = blockIdx.y;
    const int idx = blockIdx.x * 256 + threadIdx.x;   // over 128*64
    const int n = idx >> 6, k = idx & 63;
    float v = 0.f;
    if (n < GATES) {
        const float* wrow = g_wih + ((size_t)(li + 1) * GATES + n) * HID;
        if (k < HID) {
            for (int j = 0; j < HID; ++j) v += wrow[j] * w2[((size_t)li * HID + j) * HID + k];
        } else if (k == 63) {
            v = g_bih[(size_t)(li + 1) * GATES + n];
            for (int j = 0; j < HID; ++j) v += wrow[j] * b2[(size_t)li * HID + j];
        }
    }
    out[(size_t)li * 128 * 64 + idx] = __float2half(v);
}

__global__ __launch_bounds__(256) void prep_f16cvt(
    const float* __restrict__ w, _Float16* __restrict__ o, int n)
{
    const int i = blockIdx.x * 256 + threadIdx.x;
    if (i < n) o[i] = (_Float16)w[i];
}

// ---------------- MFMA gate precompute (R7-verified; padded-row addressing) ----------------
template<int MODE>
__global__ __launch_bounds__(256) void precomp_mfma(
    const void* in_, _Float16* xp,
    const _Float16* __restrict__ wihpad,  // [128][KP]
    const _Float16* __restrict__ w1pad,   // [48][64] (MODE 2 only)
    int nrows)
{
    __shared__ _Float16 s_v[4][1024];     // per-wave 2KB swizzled V tile [16][64]
    const int tid  = threadIdx.x;
    const int wid  = tid >> 6, lane = tid & 63;
    const int g    = lane >> 4, r = lane & 15;

    constexpr int KP  = (MODE == 0) ? 32 : 64;
    constexpr int NKS = KP / 32;

    half8 bw[8][NKS];
    #pragma unroll
    for (int t = 0; t < 8; ++t)
        #pragma unroll
        for (int ks = 0; ks < NKS; ++ks)
            bw[t][ks] = *reinterpret_cast<const half8*>(wihpad + (t * 16 + r) * KP + ks * 32 + g * 8);

    half8 b1f[3][2];
    char* myv = nullptr;
    if constexpr (MODE == 2) {
        #pragma unroll
        for (int t = 0; t < 3; ++t)
            #pragma unroll
            for (int ks = 0; ks < 2; ++ks)
                b1f[t][ks] = *reinterpret_cast<const half8*>(w1pad + (t * 16 + r) * 64 + ks * 32 + g * 8);
        myv = (char*)&s_v[wid][0];
        uint4 z; z.x = z.y = z.z = z.w = 0u;
        *reinterpret_cast<uint4*>(myv + lane * 32)      = z;
        *reinterpret_cast<uint4*>(myv + lane * 32 + 16) = z;
        wavesync();
        if (lane < 16)
            *reinterpret_cast<_Float16*>(myv + lane * 128 + (126 ^ ((lane & 7) << 4))) = (_Float16)1.f;
        wavesync();
    }

    const int w0     = blockIdx.x * 4 + wid;
    const int stride = gridDim.x * 64;

    for (int rb = w0 * 16; rb < nrows; rb += stride) {
        half8 a0, a1;
        if constexpr (MODE == 0) {
            const float* xr = (const float*)in_ + (size_t)(rb + r) * 20;
            if (g < 2) {
                const float4 v0 = *reinterpret_cast<const float4*>(xr + g * 8);
                const float4 v1 = *reinterpret_cast<const float4*>(xr + g * 8 + 4);
                a0[0]=(_Float16)v0.x; a0[1]=(_Float16)v0.y; a0[2]=(_Float16)v0.z; a0[3]=(_Float16)v0.w;
                a0[4]=(_Float16)v1.x; a0[5]=(_Float16)v1.y; a0[6]=(_Float16)v1.z; a0[7]=(_Float16)v1.w;
            } else if (g == 2) {
                const float4 v0 = *reinterpret_cast<const float4*>(xr + 16);
                a0[0]=(_Float16)v0.x; a0[1]=(_Float16)v0.y; a0[2]=(_Float16)v0.z; a0[3]=(_Float16)v0.w;
                a0[4]=(_Float16)0.f; a0[5]=(_Float16)0.f; a0[6]=(_Float16)0.f; a0[7]=(_Float16)0.f;
            } else {
                #pragma unroll
                for (int j = 0; j < 8; ++j) a0[j] = (_Float16)0.f;
                a0[7] = (_Float16)1.f;    // bias slot k=31
            }
        } else {
            const _Float16* hr = (const _Float16*)in_ + rowoff(rb + r);
            a0 = *reinterpret_cast<const half8*>(hr + g * 8);          // k 0..31
            if (g == 0) {
                a1 = *reinterpret_cast<const half8*>(hr + 32);         // k 32..39
            } else {
                #pragma unroll
                for (int j = 0; j < 8; ++j) a1[j] = (_Float16)0.f;
                if (g == 3) a1[7] = (_Float16)1.f;                     // bias slot k=63
            }
        }

        if constexpr (MODE == 2) {
            #pragma unroll
            for (int t = 0; t < 3; ++t) {
                f32x4 acc = {0.f, 0.f, 0.f, 0.f};
                acc = __builtin_amdgcn_mfma_f32_16x16x32_f16(a0, b1f[t][0], acc, 0, 0, 0);
                acc = __builtin_amdgcn_mfma_f32_16x16x32_f16(a1, b1f[t][1], acc, 0, 0, 0);
                const int n2 = (t * 16 + r) * 2;                       // byte col
                #pragma unroll
                for (int reg = 0; reg < 4; ++reg) {
                    const int m = g * 4 + reg;
                    float v = acc[reg];
                    v = v > 0.f ? v : 0.01f * v;
                    *reinterpret_cast<_Float16*>(myv + m * 128 + (n2 ^ ((m & 7) << 4))) = (_Float16)v;
                }
            }
            wavesync();
            const int sw = (r & 7) << 4;
            a0 = *reinterpret_cast<const half8*>(myv + r * 128 + ((g * 16) ^ sw));
            a1 = *reinterpret_cast<const half8*>(myv + r * 128 + ((64 + g * 16) ^ sw));
        }

        #pragma unroll
        for (int t = 0; t < 8; ++t) {
            f32x4 acc = {0.f, 0.f, 0.f, 0.f};
            acc = __builtin_amdgcn_mfma_f32_16x16x32_f16(a0, bw[t][0], acc, 0, 0, 0);
            if constexpr (NKS == 2)
                acc = __builtin_amdgcn_mfma_f32_16x16x32_f16(a1, bw[t][1], acc, 0, 0, 0);
            const int n = t * 16 + r;
            if (n < GATES) {
                #pragma unroll
                for (int reg = 0; reg < 4; ++reg) {
                    const int m = g * 4 + reg;
                    xp[rowoff(rb + m) + n] = (_Float16)acc[reg];
                }
            }
        }
    }
}

// ---------------- recurrence: TRUE register weights via LDS-staging + clobber ----------------
// Weights go global -> LDS -> 40 packed-f16 VGPRs before the loop. The in-loop
// wavesync "memory" clobber makes the LDS source non-invariant, so the compiler
// CANNOT rematerialize the register weights as reloads (the R8-R10 failure was
// global-const loads, which ARE provably invariant). Junk removal: padded xp
// (ROWSP rows) -> unconditional prefetch (no branch); pointer-bump addressing
// (no per-step muls); unroll 4 (rotation movs vanish via renaming).
__global__ __launch_bounds__(64) void gru_recR(
    __half* __restrict__ xp,            // [CB, ROWSP, 120], h written into [t][0:40]
    const _Float16* __restrict__ whh16, // [120][40] f16
    const float* __restrict__ bhh)      // [120]
{
    __shared__ __align__(16) _Float16 s_w[GATES * HID];  // 9600 B staging
    __shared__ __align__(16) _Float16 s_h[64];

    const int lane = threadIdx.x;
    const int e    = blockIdx.x;

    for (int idx = lane; idx < (GATES * HID) / 8; idx += 64)
        reinterpret_cast<uint4*>(s_w)[idx] = reinterpret_cast<const uint4*>(whh16)[idx];

    const int gA = lane;
    const int gB = (lane < 40) ? (80 + lane) : ((lane < 56) ? (24 + lane) : lane);
    const float bhA = bhh[gA], bhB = bhh[gB];

    __half* xpb = xp + (size_t)e * ROWSP * GATES;

    float hreg = 0.f;
    s_h[lane] = (_Float16)0.f;
    wavesync();   // staging + s_h init complete

    // pull this lane's 2 weight rows from LDS into registers (40 dwords)
    fp16x2 wA[20], wB[20];
    {
        const _Float16* wrA = s_w + gA * HID;
        const _Float16* wrB = s_w + gB * HID;
        #pragma unroll
        for (int k = 0; k < 5; ++k) {
            const half8 wa = *reinterpret_cast<const half8*>(wrA + k * 8);
            const half8 wb = *reinterpret_cast<const half8*>(wrB + k * 8);
            wA[4*k+0] = ext2<0>(wa); wB[4*k+0] = ext2<0>(wb);
            wA[4*k+1] = ext2<1>(wa); wB[4*k+1] = ext2<1>(wb);
            wA[4*k+2] = ext2<2>(wa); wB[4*k+2] = ext2<2>(wb);
            wA[4*k+3] = ext2<3>(wa); wB[4*k+3] = ext2<3>(wb);
        }
    }
    wavesync();

    // 3-deep prefetch, pointer-bumped; padded rows make it unconditional
    __half a0 = xpb[gA],             c0 = xpb[gB];
    __half a1 = xpb[GATES + gA],     c1 = xpb[GATES + gB];
    __half a2 = xpb[2 * GATES + gA], c2 = xpb[2 * GATES + gB];
    const __half* pfA = xpb + 3 * GATES + gA;
    const __half* pfB = xpb + 3 * GATES + gB;
    __half*       pst = xpb + lane;

    #pragma unroll 4
    for (int t = 0; t < T_STEPS; ++t) {
        const __half a3 = *pfA;  pfA += GATES;
        const __half c3 = *pfB;  pfB += GATES;

        const half8 p0 = *reinterpret_cast<const half8*>(&s_h[0]);
        const half8 p1 = *reinterpret_cast<const half8*>(&s_h[8]);
        const half8 p2 = *reinterpret_cast<const half8*>(&s_h[16]);
        const half8 p3 = *reinterpret_cast<const half8*>(&s_h[24]);
        const half8 p4 = *reinterpret_cast<const half8*>(&s_h[32]);

        float A0 = 0.f, A1 = 0.f, A2 = 0.f, A3 = 0.f;
        float B0 = 0.f, B1 = 0.f, B2 = 0.f, B3 = 0.f;
        A0 = fdot2(ext2<0>(p0), wA[ 0], A0); B0 = fdot2(ext2<0>(p0), wB[ 0], B0);
        A1 = fdot2(ext2<1>(p0), wA[ 1], A1); B1 = fdot2(ext2<1>(p0), wB[ 1], B1);
        A2 = fdot2(ext2<2>(p0), wA[ 2], A2); B2 = fdot2(ext2<2>(p0), wB[ 2], B2);
        A3 = fdot2(ext2<3>(p0), wA[ 3], A3); B3 = fdot2(ext2<3>(p0), wB[ 3], B3);
        A0 = fdot2(ext2<0>(p1), wA[ 4], A0); B0 = fdot2(ext2<0>(p1), wB[ 4], B0);
        A1 = fdot2(ext2<1>(p1), wA[ 5], A1); B1 = fdot2(ext2<1>(p1), wB[ 5], B1);
        A2 = fdot2(ext2<2>(p1), wA[ 6], A2); B2 = fdot2(ext2<2>(p1), wB[ 6], B2);
        A3 = fdot2(ext2<3>(p1), wA[ 7], A3); B3 = fdot2(ext2<3>(p1), wB[ 7], B3);
        A0 = fdot2(ext2<0>(p2), wA[ 8], A0); B0 = fdot2(ext2<0>(p2), wB[ 8], B0);
        A1 = fdot2(ext2<1>(p2), wA[ 9], A1); B1 = fdot2(ext2<1>(p2), wB[ 9], B1);
        A2 = fdot2(ext2<2>(p2), wA[10], A2); B2 = fdot2(ext2<2>(p2), wB[10], B2);
        A3 = fdot2(ext2<3>(p2), wA[11], A3); B3 = fdot2(ext2<3>(p2), wB[11], B3);
        A0 = fdot2(ext2<0>(p3), wA[12], A0); B0 = fdot2(ext2<0>(p3), wB[12], B0);
        A1 = fdot2(ext2<1>(p3), wA[13], A1); B1 = fdot2(ext2<1>(p3), wB[13], B1);
        A2 = fdot2(ext2<2>(p3), wA[14], A2); B2 = fdot2(ext2<2>(p3), wB[14], B2);
        A3 = fdot2(ext2<3>(p3), wA[15], A3); B3 = fdot2(ext2<3>(p3), wB[15], B3);
        A0 = fdot2(ext2<0>(p4), wA[16], A0); B0 = fdot2(ext2<0>(p4), wB[16], B0);
        A1 = fdot2(ext2<1>(p4), wA[17], A1); B1 = fdot2(ext2<1>(p4), wB[17], B1);
        A2 = fdot2(ext2<2>(p4), wA[18], A2); B2 = fdot2(ext2<2>(p4), wB[18], B2);
        A3 = fdot2(ext2<3>(p4), wA[19], A3); B3 = fdot2(ext2<3>(p4), wB[19], B3);

        const float shA = bhA + ((A0 + A2) + (A1 + A3));
        const float shB = bhB + ((B0 + B2) + (B1 + B3));
        const float xA  = __half2float(a0);
        const float xB  = __half2float(c0);
        const float sumA = xA + shA;
        const float sumB = xB + shB;
        // z_l: lane 40+l (sumA) for l<24, lane 16+l (sumB) for l>=24. All lanes execute.
        const float zA = bperm(40 + lane, sumA);
        const float zB = bperm(16 + lane, sumB);

        if (lane < HID) {
            const float rr  = sigm(sumA);
            const float z   = sigm((lane < 24) ? zA : zB);
            const float pre = xB + rr * shB;          // x_n + r*h_n (biases included)
            const float ex  = __expf(-2.f * pre);
            const float nn  = (1.f - ex) / (1.f + ex);
            hreg = (1.f - z) * nn + z * hreg;
            s_h[lane] = (_Float16)hreg;
            *pst = __float2half(hreg);
        }
        pst += GATES;
        a0 = a1; c0 = c1; a1 = a2; c1 = c2; a2 = a3; c2 = c3;
        wavesync();   // s_h ordered for next step; clobber pins weights in regs
    }
}

// ---------------- head ----------------
__global__ __launch_bounds__(256) void final_head(
    const __half* __restrict__ xpbuf,  // padded buffer base
    float* __restrict__ outp,          // [CB]
    const float* __restrict__ w1, const float* __restrict__ b1,
    const float* __restrict__ wl, const float* __restrict__ bl, int n)
{
    __shared__ float s_w1[HID][HID + 1];
    __shared__ float s_b1[HID];
    __shared__ float s_wl[HID];
    for (int i = threadIdx.x; i < HID * HID; i += 256) s_w1[i / HID][i % HID] = w1[i];
    if (threadIdx.x < HID) { s_b1[threadIdx.x] = b1[threadIdx.x]; s_wl[threadIdx.x] = wl[threadIdx.x]; }
    __syncthreads();
    const int e = blockIdx.x * 256 + threadIdx.x;
    if (e >= n) return;

    const __half* hbase = xpbuf + ((size_t)e * ROWSP + (T_STEPS - 1)) * GATES;
    alignas(16) __half hx[HID];
    const uint4* hr = reinterpret_cast<const uint4*>(hbase);
    #pragma unroll
    for (int q = 0; q < HID / 8; ++q) reinterpret_cast<uint4*>(hx)[q] = hr[q];
    float h[HID];
    #pragma unroll
    for (int k = 0; k < HID; ++k) h[k] = __half2float(hx[k]);

    float acc = bl[0];
    #pragma unroll
    for (int u = 0; u < HID; ++u) {
        float a = s_b1[u];
        #pragma unroll
        for (int d = 0; d < HID; ++d) a += s_w1[u][d] * h[d];
        a = a > 0.f ? a : 0.01f * a;
        acc += a * s_wl[u];
    }
    outp[e] = 1.f / (1.f + __expf(-acc));
}

extern "C" void kernel_launch(void* const* d_in, const int* in_sizes, int n_in,
                              void* d_out, int out_size, void* d_ws, size_t ws_size,
                              hipStream_t stream)
{
    const float* x      = (const float*)d_in[0];
    const float* g0_wih = (const float*)d_in[1];
    const float* g0_whh = (const float*)d_in[2];
    const float* g0_bih = (const float*)d_in[3];
    const float* g0_bhh = (const float*)d_in[4];
    const float* g_wih  = (const float*)d_in[5];   // [4,120,40]
    const float* g_whh  = (const float*)d_in[6];   // [4,120,40]
    const float* g_bih  = (const float*)d_in[7];   // [4,120]
    const float* g_bhh  = (const float*)d_in[8];   // [4,120]
    const float* mlp_w1 = (const float*)d_in[9];   // [4,40,40]
    const float* mlp_b1 = (const float*)d_in[10];  // [4,40]
    const float* mlp_w2 = (const float*)d_in[11];  // [3,40,40]
    const float* mlp_b2 = (const float*)d_in[12];  // [3,40]
    const float* w_last = (const float*)d_in[13];  // [1,40]
    const float* b_last = (const float*)d_in[14];  // [1]

    const int B = in_sizes[0] / (T_STEPS * 20);
    float* out = (float*)d_out;

    // ws (halfs): [w1pad 3*3072][effpad 3*8192][g0pad 4096][g1pad 8192][whh16 5*4800] then xp
    __half* wsz    = (__half*)d_ws;
    __half* w1pad  = wsz;                       // 9216
    __half* effpad = wsz + 3 * 3072;            // 24576
    __half* g0pad  = wsz + 9216 + 3 * 8192;     // 4096
    __half* g1pad  = g0pad + 4096;              // 8192
    _Float16* whh16 = (_Float16*)(wsz + 46080); // 24000
    _Float16* xpbuf = (_Float16*)(wsz + 70080); // 140160 B of weights, 16B aligned
    const size_t ws_rem = ws_size - 70080 * sizeof(__half);

    for (int li = 0; li < 3; ++li)
        prep_pad<<<dim3(12), dim3(256), 0, stream>>>(
            mlp_w1 + li * 1600, mlp_b1 + li * 40, w1pad + li * 3072, 40, 40, 64);
    prep_pad<<<dim3(16), dim3(256), 0, stream>>>(g0_wih, g0_bih, g0pad, 120, 20, 32);
    prep_pad<<<dim3(32), dim3(256), 0, stream>>>(g_wih, g_bih, g1pad, 120, 40, 64);
    prep_eff<<<dim3(32, 3), dim3(256), 0, stream>>>(g_wih, g_bih, mlp_w2, mlp_b2, effpad);
    prep_f16cvt<<<dim3(19), dim3(256), 0, stream>>>(g0_whh, whh16, 4800);
    prep_f16cvt<<<dim3(75), dim3(256), 0, stream>>>(g_whh, whh16 + 4800, 19200);

    const size_t per_e = (size_t)ROWSP * GATES * sizeof(__half);  // padded element footprint
    int CB = B;
    while ((size_t)CB * per_e > ws_rem && CB > 64) CB >>= 1;

    for (int c = 0; c < B; c += CB) {
        const int  nrows = CB * T_STEPS;
        const dim3 pgrd(nrows / 512), pblk(256);
        const dim3 rgrd(CB), rblk(64);
        const float* xc = x + (size_t)c * T_STEPS * 20;

        precomp_mfma<0><<<pgrd, pblk, 0, stream>>>(
            xc, xpbuf, (const _Float16*)g0pad, nullptr, nrows);
        gru_recR<<<rgrd, rblk, 0, stream>>>((__half*)xpbuf, whh16, g0_bhh);

        precomp_mfma<1><<<pgrd, pblk, 0, stream>>>(
            xpbuf, xpbuf, (const _Float16*)g1pad, nullptr, nrows);
        gru_recR<<<rgrd, rblk, 0, stream>>>((__half*)xpbuf, whh16 + 4800, g_bhh + 0 * 120);

        for (int li = 0; li < 3; ++li) {
            precomp_mfma<2><<<pgrd, pblk, 0, stream>>>(
                xpbuf, xpbuf, (const _Float16*)(effpad + li * 8192),
                (const _Float16*)(w1pad + li * 3072), nrows);
            gru_recR<<<rgrd, rblk, 0, stream>>>(
                (__half*)xpbuf, whh16 + 4800 + (li + 1) * 4800, g_bhh + (li + 1) * 120);
        }

        final_head<<<dim3((CB + 255) / 256), dim3(256), 0, stream>>>(
            (const __half*)xpbuf, out + c,
            mlp_w1 + 3 * 1600, mlp_b1 + 3 * 40, w_last, b_last, CB);
    }
}

// Round 16
// 1670.000 us; speedup vs baseline: 2.9145x; 1.2125x over previous
//
#include <hip/hip_runtime.h>
#include <hip/hip_fp16.h>
#include <cstdint>
#include <cstddef>

#define T_STEPS 512
#define ROWSP   516          // padded rows per element (3-deep unconditional prefetch)
#define HID 40
#define GATES 120

typedef _Float16 half8 __attribute__((ext_vector_type(8)));
typedef _Float16 fp16x2 __attribute__((ext_vector_type(2)));
typedef float f32x4 __attribute__((ext_vector_type(4)));

__device__ __forceinline__ void wavesync() { asm volatile("s_waitcnt lgkmcnt(0)" ::: "memory"); }
__device__ __forceinline__ float bperm(int srclane, float v) {
    return __int_as_float(__builtin_amdgcn_ds_bpermute(srclane << 2, __float_as_int(v)));
}
__device__ __forceinline__ float sigm(float x) { return 1.f / (1.f + __expf(-x)); }

template<int J>
__device__ __forceinline__ fp16x2 ext2(half8 v) {
    return __builtin_shufflevector(v, v, 2 * J, 2 * J + 1);
}

#if __has_builtin(__builtin_amdgcn_fdot2)
__device__ __forceinline__ float fdot2(fp16x2 a, fp16x2 b, float c) {
    return __builtin_amdgcn_fdot2(a, b, c, false);
}
#else
__device__ __forceinline__ float fdot2(fp16x2 a, fp16x2 b, float c) {
    return c + (float)a[0] * (float)b[0] + (float)a[1] * (float)b[1];
}
#endif

// padded-row byte mapping: row i (linear e*512+t) lives at (e*516+t)*GATES
__device__ __forceinline__ size_t rowoff(int row) {
    return ((size_t)(row >> 9) * ROWSP + (row & 511)) * GATES;
}

// ---------------- weight prep (run once, tiny) ----------------
__global__ __launch_bounds__(256) void prep_pad(
    const float* __restrict__ w, const float* __restrict__ b,
    __half* __restrict__ out, int N, int K, int KPAD)
{
    const int idx = blockIdx.x * 256 + threadIdx.x;
    const int n = idx / KPAD, k = idx - n * KPAD;
    float v = 0.f;
    if (n < N) {
        if (k < K) v = w[n * K + k];
        else if (k == KPAD - 1) v = b[n];
    }
    out[idx] = __float2half(v);
}

__global__ __launch_bounds__(256) void prep_eff(
    const float* __restrict__ g_wih, const float* __restrict__ g_bih,
    const float* __restrict__ w2, const float* __restrict__ b2,
    __half* __restrict__ out)
{
    const int li  = blockIdx.y;
    const int idx = blockIdx.x * 256 + threadIdx.x;   // over 128*64
    const int n = idx >> 6, k = idx & 63;
    float v = 0.f;
    if (n < GATES) {
        const float* wrow = g_wih + ((size_t)(li + 1) * GATES + n) * HID;
        if (k < HID) {
            for (int j = 0; j < HID; ++j) v += wrow[j] * w2[((size_t)li * HID + j) * HID + k];
        } else if (k == 63) {
            v = g_bih[(size_t)(li + 1) * GATES + n];
            for (int j = 0; j < HID; ++j) v += wrow[j] * b2[(size_t)li * HID + j];
        }
    }
    out[(size_t)li * 128 * 64 + idx] = __float2half(v);
}

__global__ __launch_bounds__(256) void prep_f16cvt(
    const float* __restrict__ w, _Float16* __restrict__ o, int n)
{
    const int i = blockIdx.x * 256 + threadIdx.x;
    if (i < n) o[i] = (_Float16)w[i];
}

// ---------------- MFMA gate precompute (R7-verified; padded-row addressing) ----------------
template<int MODE>
__global__ __launch_bounds__(256) void precomp_mfma(
    const void* in_, _Float16* xp,
    const _Float16* __restrict__ wihpad,  // [128][KP]
    const _Float16* __restrict__ w1pad,   // [48][64] (MODE 2 only)
    int nrows)
{
    __shared__ _Float16 s_v[4][1024];     // per-wave 2KB swizzled V tile [16][64]
    const int tid  = threadIdx.x;
    const int wid  = tid >> 6, lane = tid & 63;
    const int g    = lane >> 4, r = lane & 15;

    constexpr int KP  = (MODE == 0) ? 32 : 64;
    constexpr int NKS = KP / 32;

    half8 bw[8][NKS];
    #pragma unroll
    for (int t = 0; t < 8; ++t)
        #pragma unroll
        for (int ks = 0; ks < NKS; ++ks)
            bw[t][ks] = *reinterpret_cast<const half8*>(wihpad + (t * 16 + r) * KP + ks * 32 + g * 8);

    half8 b1f[3][2];
    char* myv = nullptr;
    if constexpr (MODE == 2) {
        #pragma unroll
        for (int t = 0; t < 3; ++t)
            #pragma unroll
            for (int ks = 0; ks < 2; ++ks)
                b1f[t][ks] = *reinterpret_cast<const half8*>(w1pad + (t * 16 + r) * 64 + ks * 32 + g * 8);
        myv = (char*)&s_v[wid][0];
        uint4 z; z.x = z.y = z.z = z.w = 0u;
        *reinterpret_cast<uint4*>(myv + lane * 32)      = z;
        *reinterpret_cast<uint4*>(myv + lane * 32 + 16) = z;
        wavesync();
        if (lane < 16)
            *reinterpret_cast<_Float16*>(myv + lane * 128 + (126 ^ ((lane & 7) << 4))) = (_Float16)1.f;
        wavesync();
    }

    const int w0     = blockIdx.x * 4 + wid;
    const int stride = gridDim.x * 64;

    for (int rb = w0 * 16; rb < nrows; rb += stride) {
        half8 a0, a1;
        if constexpr (MODE == 0) {
            const float* xr = (const float*)in_ + (size_t)(rb + r) * 20;
            if (g < 2) {
                const float4 v0 = *reinterpret_cast<const float4*>(xr + g * 8);
                const float4 v1 = *reinterpret_cast<const float4*>(xr + g * 8 + 4);
                a0[0]=(_Float16)v0.x; a0[1]=(_Float16)v0.y; a0[2]=(_Float16)v0.z; a0[3]=(_Float16)v0.w;
                a0[4]=(_Float16)v1.x; a0[5]=(_Float16)v1.y; a0[6]=(_Float16)v1.z; a0[7]=(_Float16)v1.w;
            } else if (g == 2) {
                const float4 v0 = *reinterpret_cast<const float4*>(xr + 16);
                a0[0]=(_Float16)v0.x; a0[1]=(_Float16)v0.y; a0[2]=(_Float16)v0.z; a0[3]=(_Float16)v0.w;
                a0[4]=(_Float16)0.f; a0[5]=(_Float16)0.f; a0[6]=(_Float16)0.f; a0[7]=(_Float16)0.f;
            } else {
                #pragma unroll
                for (int j = 0; j < 8; ++j) a0[j] = (_Float16)0.f;
                a0[7] = (_Float16)1.f;    // bias slot k=31
            }
        } else {
            const _Float16* hr = (const _Float16*)in_ + rowoff(rb + r);
            a0 = *reinterpret_cast<const half8*>(hr + g * 8);          // k 0..31
            if (g == 0) {
                a1 = *reinterpret_cast<const half8*>(hr + 32);         // k 32..39
            } else {
                #pragma unroll
                for (int j = 0; j < 8; ++j) a1[j] = (_Float16)0.f;
                if (g == 3) a1[7] = (_Float16)1.f;                     // bias slot k=63
            }
        }

        if constexpr (MODE == 2) {
            #pragma unroll
            for (int t = 0; t < 3; ++t) {
                f32x4 acc = {0.f, 0.f, 0.f, 0.f};
                acc = __builtin_amdgcn_mfma_f32_16x16x32_f16(a0, b1f[t][0], acc, 0, 0, 0);
                acc = __builtin_amdgcn_mfma_f32_16x16x32_f16(a1, b1f[t][1], acc, 0, 0, 0);
                const int n2 = (t * 16 + r) * 2;                       // byte col
                #pragma unroll
                for (int reg = 0; reg < 4; ++reg) {
                    const int m = g * 4 + reg;
                    float v = acc[reg];
                    v = v > 0.f ? v : 0.01f * v;
                    *reinterpret_cast<_Float16*>(myv + m * 128 + (n2 ^ ((m & 7) << 4))) = (_Float16)v;
                }
            }
            wavesync();
            const int sw = (r & 7) << 4;
            a0 = *reinterpret_cast<const half8*>(myv + r * 128 + ((g * 16) ^ sw));
            a1 = *reinterpret_cast<const half8*>(myv + r * 128 + ((64 + g * 16) ^ sw));
        }

        #pragma unroll
        for (int t = 0; t < 8; ++t) {
            f32x4 acc = {0.f, 0.f, 0.f, 0.f};
            acc = __builtin_amdgcn_mfma_f32_16x16x32_f16(a0, bw[t][0], acc, 0, 0, 0);
            if constexpr (NKS == 2)
                acc = __builtin_amdgcn_mfma_f32_16x16x32_f16(a1, bw[t][1], acc, 0, 0, 0);
            const int n = t * 16 + r;
            if (n < GATES) {
                #pragma unroll
                for (int reg = 0; reg < 4; ++reg) {
                    const int m = g * 4 + reg;
                    xp[rowoff(rb + m) + n] = (_Float16)acc[reg];
                }
            }
        }
    }
}

// ---------------- recurrence: LDS-staged register weights + true 2-wave budget ----------------
// R15 structure. NEW: amdgpu_waves_per_eu(2,2) — the grid is 2048 single-wave
// blocks (max 2 waves/SIMD), but the backend's default targets 8 waves/SIMD
// (VGPR<=64), which forced per-step LDS weight re-reads (VGPR_Count=52). Telling
// it the truth raises the budget to 256 so the 40 weight dwords stay resident.
__global__ __launch_bounds__(64)
__attribute__((amdgpu_waves_per_eu(2, 2)))
void gru_recR(
    __half* __restrict__ xp,            // [CB, ROWSP, 120], h written into [t][0:40]
    const _Float16* __restrict__ whh16, // [120][40] f16
    const float* __restrict__ bhh)      // [120]
{
    __shared__ __align__(16) _Float16 s_w[GATES * HID];  // 9600 B staging
    __shared__ __align__(16) _Float16 s_h[64];

    const int lane = threadIdx.x;
    const int e    = blockIdx.x;

    for (int idx = lane; idx < (GATES * HID) / 8; idx += 64)
        reinterpret_cast<uint4*>(s_w)[idx] = reinterpret_cast<const uint4*>(whh16)[idx];

    const int gA = lane;
    const int gB = (lane < 40) ? (80 + lane) : ((lane < 56) ? (24 + lane) : lane);
    const float bhA = bhh[gA], bhB = bhh[gB];

    __half* xpb = xp + (size_t)e * ROWSP * GATES;

    float hreg = 0.f;
    s_h[lane] = (_Float16)0.f;
    wavesync();   // staging + s_h init complete

    // pull this lane's 2 weight rows from LDS into registers (40 dwords)
    fp16x2 wA[20], wB[20];
    {
        const _Float16* wrA = s_w + gA * HID;
        const _Float16* wrB = s_w + gB * HID;
        #pragma unroll
        for (int k = 0; k < 5; ++k) {
            const half8 wa = *reinterpret_cast<const half8*>(wrA + k * 8);
            const half8 wb = *reinterpret_cast<const half8*>(wrB + k * 8);
            wA[4*k+0] = ext2<0>(wa); wB[4*k+0] = ext2<0>(wb);
            wA[4*k+1] = ext2<1>(wa); wB[4*k+1] = ext2<1>(wb);
            wA[4*k+2] = ext2<2>(wa); wB[4*k+2] = ext2<2>(wb);
            wA[4*k+3] = ext2<3>(wa); wB[4*k+3] = ext2<3>(wb);
        }
    }
    wavesync();

    // 3-deep prefetch, pointer-bumped; padded rows make it unconditional
    __half a0 = xpb[gA],             c0 = xpb[gB];
    __half a1 = xpb[GATES + gA],     c1 = xpb[GATES + gB];
    __half a2 = xpb[2 * GATES + gA], c2 = xpb[2 * GATES + gB];
    const __half* pfA = xpb + 3 * GATES + gA;
    const __half* pfB = xpb + 3 * GATES + gB;
    __half*       pst = xpb + lane;

    #pragma unroll 4
    for (int t = 0; t < T_STEPS; ++t) {
        const __half a3 = *pfA;  pfA += GATES;
        const __half c3 = *pfB;  pfB += GATES;

        const half8 p0 = *reinterpret_cast<const half8*>(&s_h[0]);
        const half8 p1 = *reinterpret_cast<const half8*>(&s_h[8]);
        const half8 p2 = *reinterpret_cast<const half8*>(&s_h[16]);
        const half8 p3 = *reinterpret_cast<const half8*>(&s_h[24]);
        const half8 p4 = *reinterpret_cast<const half8*>(&s_h[32]);

        float A0 = 0.f, A1 = 0.f, A2 = 0.f, A3 = 0.f;
        float B0 = 0.f, B1 = 0.f, B2 = 0.f, B3 = 0.f;
        A0 = fdot2(ext2<0>(p0), wA[ 0], A0); B0 = fdot2(ext2<0>(p0), wB[ 0], B0);
        A1 = fdot2(ext2<1>(p0), wA[ 1], A1); B1 = fdot2(ext2<1>(p0), wB[ 1], B1);
        A2 = fdot2(ext2<2>(p0), wA[ 2], A2); B2 = fdot2(ext2<2>(p0), wB[ 2], B2);
        A3 = fdot2(ext2<3>(p0), wA[ 3], A3); B3 = fdot2(ext2<3>(p0), wB[ 3], B3);
        A0 = fdot2(ext2<0>(p1), wA[ 4], A0); B0 = fdot2(ext2<0>(p1), wB[ 4], B0);
        A1 = fdot2(ext2<1>(p1), wA[ 5], A1); B1 = fdot2(ext2<1>(p1), wB[ 5], B1);
        A2 = fdot2(ext2<2>(p1), wA[ 6], A2); B2 = fdot2(ext2<2>(p1), wB[ 6], B2);
        A3 = fdot2(ext2<3>(p1), wA[ 7], A3); B3 = fdot2(ext2<3>(p1), wB[ 7], B3);
        A0 = fdot2(ext2<0>(p2), wA[ 8], A0); B0 = fdot2(ext2<0>(p2), wB[ 8], B0);
        A1 = fdot2(ext2<1>(p2), wA[ 9], A1); B1 = fdot2(ext2<1>(p2), wB[ 9], B1);
        A2 = fdot2(ext2<2>(p2), wA[10], A2); B2 = fdot2(ext2<2>(p2), wB[10], B2);
        A3 = fdot2(ext2<3>(p2), wA[11], A3); B3 = fdot2(ext2<3>(p2), wB[11], B3);
        A0 = fdot2(ext2<0>(p3), wA[12], A0); B0 = fdot2(ext2<0>(p3), wB[12], B0);
        A1 = fdot2(ext2<1>(p3), wA[13], A1); B1 = fdot2(ext2<1>(p3), wB[13], B1);
        A2 = fdot2(ext2<2>(p3), wA[14], A2); B2 = fdot2(ext2<2>(p3), wB[14], B2);
        A3 = fdot2(ext2<3>(p3), wA[15], A3); B3 = fdot2(ext2<3>(p3), wB[15], B3);
        A0 = fdot2(ext2<0>(p4), wA[16], A0); B0 = fdot2(ext2<0>(p4), wB[16], B0);
        A1 = fdot2(ext2<1>(p4), wA[17], A1); B1 = fdot2(ext2<1>(p4), wB[17], B1);
        A2 = fdot2(ext2<2>(p4), wA[18], A2); B2 = fdot2(ext2<2>(p4), wB[18], B2);
        A3 = fdot2(ext2<3>(p4), wA[19], A3); B3 = fdot2(ext2<3>(p4), wB[19], B3);

        const float shA = bhA + ((A0 + A2) + (A1 + A3));
        const float shB = bhB + ((B0 + B2) + (B1 + B3));
        const float xA  = __half2float(a0);
        const float xB  = __half2float(c0);
        const float sumA = xA + shA;
        const float sumB = xB + shB;
        // z_l: lane 40+l (sumA) for l<24, lane 16+l (sumB) for l>=24. All lanes execute.
        const float zA = bperm(40 + lane, sumA);
        const float zB = bperm(16 + lane, sumB);

        if (lane < HID) {
            const float rr  = sigm(sumA);
            const float z   = sigm((lane < 24) ? zA : zB);
            const float pre = xB + rr * shB;          // x_n + r*h_n (biases included)
            const float ex  = __expf(-2.f * pre);
            const float nn  = (1.f - ex) / (1.f + ex);
            hreg = (1.f - z) * nn + z * hreg;
            s_h[lane] = (_Float16)hreg;
            *pst = __float2half(hreg);
        }
        pst += GATES;
        a0 = a1; c0 = c1; a1 = a2; c1 = c2; a2 = a3; c2 = c3;
        wavesync();   // s_h ordered for next step; clobber pins weights in regs
    }
}

// ---------------- head ----------------
__global__ __launch_bounds__(256) void final_head(
    const __half* __restrict__ xpbuf,  // padded buffer base
    float* __restrict__ outp,          // [CB]
    const float* __restrict__ w1, const float* __restrict__ b1,
    const float* __restrict__ wl, const float* __restrict__ bl, int n)
{
    __shared__ float s_w1[HID][HID + 1];
    __shared__ float s_b1[HID];
    __shared__ float s_wl[HID];
    for (int i = threadIdx.x; i < HID * HID; i += 256) s_w1[i / HID][i % HID] = w1[i];
    if (threadIdx.x < HID) { s_b1[threadIdx.x] = b1[threadIdx.x]; s_wl[threadIdx.x] = wl[threadIdx.x]; }
    __syncthreads();
    const int e = blockIdx.x * 256 + threadIdx.x;
    if (e >= n) return;

    const __half* hbase = xpbuf + ((size_t)e * ROWSP + (T_STEPS - 1)) * GATES;
    alignas(16) __half hx[HID];
    const uint4* hr = reinterpret_cast<const uint4*>(hbase);
    #pragma unroll
    for (int q = 0; q < HID / 8; ++q) reinterpret_cast<uint4*>(hx)[q] = hr[q];
    float h[HID];
    #pragma unroll
    for (int k = 0; k < HID; ++k) h[k] = __half2float(hx[k]);

    float acc = bl[0];
    #pragma unroll
    for (int u = 0; u < HID; ++u) {
        float a = s_b1[u];
        #pragma unroll
        for (int d = 0; d < HID; ++d) a += s_w1[u][d] * h[d];
        a = a > 0.f ? a : 0.01f * a;
        acc += a * s_wl[u];
    }
    outp[e] = 1.f / (1.f + __expf(-acc));
}

extern "C" void kernel_launch(void* const* d_in, const int* in_sizes, int n_in,
                              void* d_out, int out_size, void* d_ws, size_t ws_size,
                              hipStream_t stream)
{
    const float* x      = (const float*)d_in[0];
    const float* g0_wih = (const float*)d_in[1];
    const float* g0_whh = (const float*)d_in[2];
    const float* g0_bih = (const float*)d_in[3];
    const float* g0_bhh = (const float*)d_in[4];
    const float* g_wih  = (const float*)d_in[5];   // [4,120,40]
    const float* g_whh  = (const float*)d_in[6];   // [4,120,40]
    const float* g_bih  = (const float*)d_in[7];   // [4,120]
    const float* g_bhh  = (const float*)d_in[8];   // [4,120]
    const float* mlp_w1 = (const float*)d_in[9];   // [4,40,40]
    const float* mlp_b1 = (const float*)d_in[10];  // [4,40]
    const float* mlp_w2 = (const float*)d_in[11];  // [3,40,40]
    const float* mlp_b2 = (const float*)d_in[12];  // [3,40]
    const float* w_last = (const float*)d_in[13];  // [1,40]
    const float* b_last = (const float*)d_in[14];  // [1]

    const int B = in_sizes[0] / (T_STEPS * 20);
    float* out = (float*)d_out;

    // ws (halfs): [w1pad 3*3072][effpad 3*8192][g0pad 4096][g1pad 8192][whh16 5*4800] then xp
    __half* wsz    = (__half*)d_ws;
    __half* w1pad  = wsz;                       // 9216
    __half* effpad = wsz + 3 * 3072;            // 24576
    __half* g0pad  = wsz + 9216 + 3 * 8192;     // 4096
    __half* g1pad  = g0pad + 4096;              // 8192
    _Float16* whh16 = (_Float16*)(wsz + 46080); // 24000
    _Float16* xpbuf = (_Float16*)(wsz + 70080); // 140160 B of weights, 16B aligned
    const size_t ws_rem = ws_size - 70080 * sizeof(__half);

    for (int li = 0; li < 3; ++li)
        prep_pad<<<dim3(12), dim3(256), 0, stream>>>(
            mlp_w1 + li * 1600, mlp_b1 + li * 40, w1pad + li * 3072, 40, 40, 64);
    prep_pad<<<dim3(16), dim3(256), 0, stream>>>(g0_wih, g0_bih, g0pad, 120, 20, 32);
    prep_pad<<<dim3(32), dim3(256), 0, stream>>>(g_wih, g_bih, g1pad, 120, 40, 64);
    prep_eff<<<dim3(32, 3), dim3(256), 0, stream>>>(g_wih, g_bih, mlp_w2, mlp_b2, effpad);
    prep_f16cvt<<<dim3(19), dim3(256), 0, stream>>>(g0_whh, whh16, 4800);
    prep_f16cvt<<<dim3(75), dim3(256), 0, stream>>>(g_whh, whh16 + 4800, 19200);

    const size_t per_e = (size_t)ROWSP * GATES * sizeof(__half);  // padded element footprint
    int CB = B;
    while ((size_t)CB * per_e > ws_rem && CB > 64) CB >>= 1;

    for (int c = 0; c < B; c += CB) {
        const int  nrows = CB * T_STEPS;
        const dim3 pgrd(nrows / 512), pblk(256);
        const dim3 rgrd(CB), rblk(64);
        const float* xc = x + (size_t)c * T_STEPS * 20;

        precomp_mfma<0><<<pgrd, pblk, 0, stream>>>(
            xc, xpbuf, (const _Float16*)g0pad, nullptr, nrows);
        gru_recR<<<rgrd, rblk, 0, stream>>>((__half*)xpbuf, whh16, g0_bhh);

        precomp_mfma<1><<<pgrd, pblk, 0, stream>>>(
            xpbuf, xpbuf, (const _Float16*)g1pad, nullptr, nrows);
        gru_recR<<<rgrd, rblk, 0, stream>>>((__half*)xpbuf, whh16 + 4800, g_bhh + 0 * 120);

        for (int li = 0; li < 3; ++li) {
            precomp_mfma<2><<<pgrd, pblk, 0, stream>>>(
                xpbuf, xpbuf, (const _Float16*)(effpad + li * 8192),
                (const _Float16*)(w1pad + li * 3072), nrows);
            gru_recR<<<rgrd, rblk, 0, stream>>>(
                (__half*)xpbuf, whh16 + 4800 + (li + 1) * 4800, g_bhh + (li + 1) * 120);
        }

        final_head<<<dim3((CB + 255) / 256), dim3(256), 0, stream>>>(
            (const __half*)xpbuf, out + c,
            mlp_w1 + 3 * 1600, mlp_b1 + 3 * 40, w_last, b_last, CB);
    }
}

// Round 17
// 1660.179 us; speedup vs baseline: 2.9318x; 1.0059x over previous
//
#include <hip/hip_runtime.h>
#include <hip/hip_fp16.h>
#include <cstdint>
#include <cstddef>

#define T_STEPS 512
#define ROWSP   516          // padded rows per element (3-deep unconditional prefetch)
#define HID 40
#define GATES 120

typedef _Float16 half8 __attribute__((ext_vector_type(8)));
typedef _Float16 fp16x2 __attribute__((ext_vector_type(2)));
typedef float f32x4 __attribute__((ext_vector_type(4)));

__device__ __forceinline__ void wavesync() { asm volatile("s_waitcnt lgkmcnt(0)" ::: "memory"); }
__device__ __forceinline__ float bperm(int srclane, float v) {
    return __int_as_float(__builtin_amdgcn_ds_bpermute(srclane << 2, __float_as_int(v)));
}
__device__ __forceinline__ float sigm(float x) { return 1.f / (1.f + __expf(-x)); }

template<int J>
__device__ __forceinline__ fp16x2 ext2(half8 v) {
    return __builtin_shufflevector(v, v, 2 * J, 2 * J + 1);
}

// Guaranteed single-instruction dot: v_dot2_f32_f16 d, a, b, c  (d = a.x*b.x + a.y*b.y + c)
__device__ __forceinline__ float vdot2(fp16x2 a, fp16x2 b, float c) {
    float d;
    asm("v_dot2_f32_f16 %0, %1, %2, %3" : "=v"(d) : "v"(a), "v"(b), "v"(c));
    return d;
}

#if __has_builtin(__builtin_amdgcn_fdot2)
__device__ __forceinline__ float fdot2(fp16x2 a, fp16x2 b, float c) {
    return __builtin_amdgcn_fdot2(a, b, c, false);
}
#else
__device__ __forceinline__ float fdot2(fp16x2 a, fp16x2 b, float c) {
    return c + (float)a[0] * (float)b[0] + (float)a[1] * (float)b[1];
}
#endif

// padded-row byte mapping: row i (linear e*512+t) lives at (e*516+t)*GATES
__device__ __forceinline__ size_t rowoff(int row) {
    return ((size_t)(row >> 9) * ROWSP + (row & 511)) * GATES;
}

// ---------------- weight prep (run once, tiny) ----------------
__global__ __launch_bounds__(256) void prep_pad(
    const float* __restrict__ w, const float* __restrict__ b,
    __half* __restrict__ out, int N, int K, int KPAD)
{
    const int idx = blockIdx.x * 256 + threadIdx.x;
    const int n = idx / KPAD, k = idx - n * KPAD;
    float v = 0.f;
    if (n < N) {
        if (k < K) v = w[n * K + k];
        else if (k == KPAD - 1) v = b[n];
    }
    out[idx] = __float2half(v);
}

__global__ __launch_bounds__(256) void prep_eff(
    const float* __restrict__ g_wih, const float* __restrict__ g_bih,
    const float* __restrict__ w2, const float* __restrict__ b2,
    __half* __restrict__ out)
{
    const int li  = blockIdx.y;
    const int idx = blockIdx.x * 256 + threadIdx.x;   // over 128*64
    const int n = idx >> 6, k = idx & 63;
    float v = 0.f;
    if (n < GATES) {
        const float* wrow = g_wih + ((size_t)(li + 1) * GATES + n) * HID;
        if (k < HID) {
            for (int j = 0; j < HID; ++j) v += wrow[j] * w2[((size_t)li * HID + j) * HID + k];
        } else if (k == 63) {
            v = g_bih[(size_t)(li + 1) * GATES + n];
            for (int j = 0; j < HID; ++j) v += wrow[j] * b2[(size_t)li * HID + j];
        }
    }
    out[(size_t)li * 128 * 64 + idx] = __float2half(v);
}

__global__ __launch_bounds__(256) void prep_f16cvt(
    const float* __restrict__ w, _Float16* __restrict__ o, int n)
{
    const int i = blockIdx.x * 256 + threadIdx.x;
    if (i < n) o[i] = (_Float16)w[i];
}

// ---------------- MFMA gate precompute (R7-verified; padded-row addressing) ----------------
template<int MODE>
__global__ __launch_bounds__(256) void precomp_mfma(
    const void* in_, _Float16* xp,
    const _Float16* __restrict__ wihpad,  // [128][KP]
    const _Float16* __restrict__ w1pad,   // [48][64] (MODE 2 only)
    int nrows)
{
    __shared__ _Float16 s_v[4][1024];     // per-wave 2KB swizzled V tile [16][64]
    const int tid  = threadIdx.x;
    const int wid  = tid >> 6, lane = tid & 63;
    const int g    = lane >> 4, r = lane & 15;

    constexpr int KP  = (MODE == 0) ? 32 : 64;
    constexpr int NKS = KP / 32;

    half8 bw[8][NKS];
    #pragma unroll
    for (int t = 0; t < 8; ++t)
        #pragma unroll
        for (int ks = 0; ks < NKS; ++ks)
            bw[t][ks] = *reinterpret_cast<const half8*>(wihpad + (t * 16 + r) * KP + ks * 32 + g * 8);

    half8 b1f[3][2];
    char* myv = nullptr;
    if constexpr (MODE == 2) {
        #pragma unroll
        for (int t = 0; t < 3; ++t)
            #pragma unroll
            for (int ks = 0; ks < 2; ++ks)
                b1f[t][ks] = *reinterpret_cast<const half8*>(w1pad + (t * 16 + r) * 64 + ks * 32 + g * 8);
        myv = (char*)&s_v[wid][0];
        uint4 z; z.x = z.y = z.z = z.w = 0u;
        *reinterpret_cast<uint4*>(myv + lane * 32)      = z;
        *reinterpret_cast<uint4*>(myv + lane * 32 + 16) = z;
        wavesync();
        if (lane < 16)
            *reinterpret_cast<_Float16*>(myv + lane * 128 + (126 ^ ((lane & 7) << 4))) = (_Float16)1.f;
        wavesync();
    }

    const int w0     = blockIdx.x * 4 + wid;
    const int stride = gridDim.x * 64;

    for (int rb = w0 * 16; rb < nrows; rb += stride) {
        half8 a0, a1;
        if constexpr (MODE == 0) {
            const float* xr = (const float*)in_ + (size_t)(rb + r) * 20;
            if (g < 2) {
                const float4 v0 = *reinterpret_cast<const float4*>(xr + g * 8);
                const float4 v1 = *reinterpret_cast<const float4*>(xr + g * 8 + 4);
                a0[0]=(_Float16)v0.x; a0[1]=(_Float16)v0.y; a0[2]=(_Float16)v0.z; a0[3]=(_Float16)v0.w;
                a0[4]=(_Float16)v1.x; a0[5]=(_Float16)v1.y; a0[6]=(_Float16)v1.z; a0[7]=(_Float16)v1.w;
            } else if (g == 2) {
                const float4 v0 = *reinterpret_cast<const float4*>(xr + 16);
                a0[0]=(_Float16)v0.x; a0[1]=(_Float16)v0.y; a0[2]=(_Float16)v0.z; a0[3]=(_Float16)v0.w;
                a0[4]=(_Float16)0.f; a0[5]=(_Float16)0.f; a0[6]=(_Float16)0.f; a0[7]=(_Float16)0.f;
            } else {
                #pragma unroll
                for (int j = 0; j < 8; ++j) a0[j] = (_Float16)0.f;
                a0[7] = (_Float16)1.f;    // bias slot k=31
            }
        } else {
            const _Float16* hr = (const _Float16*)in_ + rowoff(rb + r);
            a0 = *reinterpret_cast<const half8*>(hr + g * 8);          // k 0..31
            if (g == 0) {
                a1 = *reinterpret_cast<const half8*>(hr + 32);         // k 32..39
            } else {
                #pragma unroll
                for (int j = 0; j < 8; ++j) a1[j] = (_Float16)0.f;
                if (g == 3) a1[7] = (_Float16)1.f;                     // bias slot k=63
            }
        }

        if constexpr (MODE == 2) {
            #pragma unroll
            for (int t = 0; t < 3; ++t) {
                f32x4 acc = {0.f, 0.f, 0.f, 0.f};
                acc = __builtin_amdgcn_mfma_f32_16x16x32_f16(a0, b1f[t][0], acc, 0, 0, 0);
                acc = __builtin_amdgcn_mfma_f32_16x16x32_f16(a1, b1f[t][1], acc, 0, 0, 0);
                const int n2 = (t * 16 + r) * 2;                       // byte col
                #pragma unroll
                for (int reg = 0; reg < 4; ++reg) {
                    const int m = g * 4 + reg;
                    float v = acc[reg];
                    v = v > 0.f ? v : 0.01f * v;
                    *reinterpret_cast<_Float16*>(myv + m * 128 + (n2 ^ ((m & 7) << 4))) = (_Float16)v;
                }
            }
            wavesync();
            const int sw = (r & 7) << 4;
            a0 = *reinterpret_cast<const half8*>(myv + r * 128 + ((g * 16) ^ sw));
            a1 = *reinterpret_cast<const half8*>(myv + r * 128 + ((64 + g * 16) ^ sw));
        }

        #pragma unroll
        for (int t = 0; t < 8; ++t) {
            f32x4 acc = {0.f, 0.f, 0.f, 0.f};
            acc = __builtin_amdgcn_mfma_f32_16x16x32_f16(a0, bw[t][0], acc, 0, 0, 0);
            if constexpr (NKS == 2)
                acc = __builtin_amdgcn_mfma_f32_16x16x32_f16(a1, bw[t][1], acc, 0, 0, 0);
            const int n = t * 16 + r;
            if (n < GATES) {
                #pragma unroll
                for (int reg = 0; reg < 4; ++reg) {
                    const int m = g * 4 + reg;
                    xp[rowoff(rb + m) + n] = (_Float16)acc[reg];
                }
            }
        }
    }
}

// ---------------- recurrence: asm v_dot2 + branch-free activation ----------------
// R16 structure (LDS-staged register weights, waves_per_eu(2,2), padded rows,
// pointer bumps). NEW: (1) inline-asm v_dot2_f32_f16 guarantees 1 VALU op per
// 2-MAC (suspected builtin expansion was ~3x the issue count); (2) activation on
// all 64 lanes, branch-free — lanes 40-63 write garbage only to already-consumed
// xp bytes [80:128) of row t and s_h[40:63] which no dot reads (safe in-place).
__global__ __launch_bounds__(64)
__attribute__((amdgpu_waves_per_eu(2, 2)))
void gru_recR(
    __half* __restrict__ xp,            // [CB, ROWSP, 120], h written into [t][0:40]
    const _Float16* __restrict__ whh16, // [120][40] f16
    const float* __restrict__ bhh)      // [120]
{
    __shared__ __align__(16) _Float16 s_w[GATES * HID];  // 9600 B staging
    __shared__ __align__(16) _Float16 s_h[64];

    const int lane = threadIdx.x;
    const int e    = blockIdx.x;

    for (int idx = lane; idx < (GATES * HID) / 8; idx += 64)
        reinterpret_cast<uint4*>(s_w)[idx] = reinterpret_cast<const uint4*>(whh16)[idx];

    const int gA = lane;
    const int gB = (lane < 40) ? (80 + lane) : ((lane < 56) ? (24 + lane) : lane);
    const float bhA = bhh[gA], bhB = bhh[gB];

    __half* xpb = xp + (size_t)e * ROWSP * GATES;

    float hreg = 0.f;
    s_h[lane] = (_Float16)0.f;
    wavesync();   // staging + s_h init complete

    // pull this lane's 2 weight rows from LDS into registers (40 dwords)
    fp16x2 wA[20], wB[20];
    {
        const _Float16* wrA = s_w + gA * HID;
        const _Float16* wrB = s_w + gB * HID;
        #pragma unroll
        for (int k = 0; k < 5; ++k) {
            const half8 wa = *reinterpret_cast<const half8*>(wrA + k * 8);
            const half8 wb = *reinterpret_cast<const half8*>(wrB + k * 8);
            wA[4*k+0] = ext2<0>(wa); wB[4*k+0] = ext2<0>(wb);
            wA[4*k+1] = ext2<1>(wa); wB[4*k+1] = ext2<1>(wb);
            wA[4*k+2] = ext2<2>(wa); wB[4*k+2] = ext2<2>(wb);
            wA[4*k+3] = ext2<3>(wa); wB[4*k+3] = ext2<3>(wb);
        }
    }
    wavesync();

    // 3-deep prefetch, pointer-bumped; padded rows make it unconditional
    __half a0 = xpb[gA],             c0 = xpb[gB];
    __half a1 = xpb[GATES + gA],     c1 = xpb[GATES + gB];
    __half a2 = xpb[2 * GATES + gA], c2 = xpb[2 * GATES + gB];
    const __half* pfA = xpb + 3 * GATES + gA;
    const __half* pfB = xpb + 3 * GATES + gB;
    __half*       pst = xpb + lane;

    #pragma unroll 4
    for (int t = 0; t < T_STEPS; ++t) {
        const __half a3 = *pfA;  pfA += GATES;
        const __half c3 = *pfB;  pfB += GATES;

        const half8 p0 = *reinterpret_cast<const half8*>(&s_h[0]);
        const half8 p1 = *reinterpret_cast<const half8*>(&s_h[8]);
        const half8 p2 = *reinterpret_cast<const half8*>(&s_h[16]);
        const half8 p3 = *reinterpret_cast<const half8*>(&s_h[24]);
        const half8 p4 = *reinterpret_cast<const half8*>(&s_h[32]);

        float A0 = 0.f, A1 = 0.f, A2 = 0.f, A3 = 0.f;
        float B0 = 0.f, B1 = 0.f, B2 = 0.f, B3 = 0.f;
        A0 = vdot2(ext2<0>(p0), wA[ 0], A0); B0 = vdot2(ext2<0>(p0), wB[ 0], B0);
        A1 = vdot2(ext2<1>(p0), wA[ 1], A1); B1 = vdot2(ext2<1>(p0), wB[ 1], B1);
        A2 = vdot2(ext2<2>(p0), wA[ 2], A2); B2 = vdot2(ext2<2>(p0), wB[ 2], B2);
        A3 = vdot2(ext2<3>(p0), wA[ 3], A3); B3 = vdot2(ext2<3>(p0), wB[ 3], B3);
        A0 = vdot2(ext2<0>(p1), wA[ 4], A0); B0 = vdot2(ext2<0>(p1), wB[ 4], B0);
        A1 = vdot2(ext2<1>(p1), wA[ 5], A1); B1 = vdot2(ext2<1>(p1), wB[ 5], B1);
        A2 = vdot2(ext2<2>(p1), wA[ 6], A2); B2 = vdot2(ext2<2>(p1), wB[ 6], B2);
        A3 = vdot2(ext2<3>(p1), wA[ 7], A3); B3 = vdot2(ext2<3>(p1), wB[ 7], B3);
        A0 = vdot2(ext2<0>(p2), wA[ 8], A0); B0 = vdot2(ext2<0>(p2), wB[ 8], B0);
        A1 = vdot2(ext2<1>(p2), wA[ 9], A1); B1 = vdot2(ext2<1>(p2), wB[ 9], B1);
        A2 = vdot2(ext2<2>(p2), wA[10], A2); B2 = vdot2(ext2<2>(p2), wB[10], B2);
        A3 = vdot2(ext2<3>(p2), wA[11], A3); B3 = vdot2(ext2<3>(p2), wB[11], B3);
        A0 = vdot2(ext2<0>(p3), wA[12], A0); B0 = vdot2(ext2<0>(p3), wB[12], B0);
        A1 = vdot2(ext2<1>(p3), wA[13], A1); B1 = vdot2(ext2<1>(p3), wB[13], B1);
        A2 = vdot2(ext2<2>(p3), wA[14], A2); B2 = vdot2(ext2<2>(p3), wB[14], B2);
        A3 = vdot2(ext2<3>(p3), wA[15], A3); B3 = vdot2(ext2<3>(p3), wB[15], B3);
        A0 = vdot2(ext2<0>(p4), wA[16], A0); B0 = vdot2(ext2<0>(p4), wB[16], B0);
        A1 = vdot2(ext2<1>(p4), wA[17], A1); B1 = vdot2(ext2<1>(p4), wB[17], B1);
        A2 = vdot2(ext2<2>(p4), wA[18], A2); B2 = vdot2(ext2<2>(p4), wB[18], B2);
        A3 = vdot2(ext2<3>(p4), wA[19], A3); B3 = vdot2(ext2<3>(p4), wB[19], B3);

        const float shA = bhA + ((A0 + A2) + (A1 + A3));
        const float shB = bhB + ((B0 + B2) + (B1 + B3));
        const float xA  = __half2float(a0);
        const float xB  = __half2float(c0);
        const float sumA = xA + shA;
        const float sumB = xB + shB;
        // z_l: lane 40+l (sumA) for l<24, lane 16+l (sumB) for l>=24. All lanes execute.
        const float zA = bperm(40 + lane, sumA);
        const float zB = bperm(16 + lane, sumB);

        // branch-free activation on all 64 lanes (lanes 40-63 produce garbage
        // written only to consumed xp bytes and unread s_h slots)
        const float rr  = sigm(sumA);
        const float z   = sigm((lane < 24) ? zA : zB);
        const float pre = xB + rr * shB;          // x_n + r*h_n (biases included)
        const float ex  = __expf(-2.f * pre);
        const float nn  = (1.f - ex) / (1.f + ex);
        hreg = (1.f - z) * nn + z * hreg;
        s_h[lane] = (_Float16)hreg;
        *pst = __float2half(hreg);
        pst += GATES;

        a0 = a1; c0 = c1; a1 = a2; c1 = c2; a2 = a3; c2 = c3;
        wavesync();   // s_h ordered for next step; clobber pins weights in regs
    }
}

// ---------------- head ----------------
__global__ __launch_bounds__(256) void final_head(
    const __half* __restrict__ xpbuf,  // padded buffer base
    float* __restrict__ outp,          // [CB]
    const float* __restrict__ w1, const float* __restrict__ b1,
    const float* __restrict__ wl, const float* __restrict__ bl, int n)
{
    __shared__ float s_w1[HID][HID + 1];
    __shared__ float s_b1[HID];
    __shared__ float s_wl[HID];
    for (int i = threadIdx.x; i < HID * HID; i += 256) s_w1[i / HID][i % HID] = w1[i];
    if (threadIdx.x < HID) { s_b1[threadIdx.x] = b1[threadIdx.x]; s_wl[threadIdx.x] = wl[threadIdx.x]; }
    __syncthreads();
    const int e = blockIdx.x * 256 + threadIdx.x;
    if (e >= n) return;

    const __half* hbase = xpbuf + ((size_t)e * ROWSP + (T_STEPS - 1)) * GATES;
    alignas(16) __half hx[HID];
    const uint4* hr = reinterpret_cast<const uint4*>(hbase);
    #pragma unroll
    for (int q = 0; q < HID / 8; ++q) reinterpret_cast<uint4*>(hx)[q] = hr[q];
    float h[HID];
    #pragma unroll
    for (int k = 0; k < HID; ++k) h[k] = __half2float(hx[k]);

    float acc = bl[0];
    #pragma unroll
    for (int u = 0; u < HID; ++u) {
        float a = s_b1[u];
        #pragma unroll
        for (int d = 0; d < HID; ++d) a += s_w1[u][d] * h[d];
        a = a > 0.f ? a : 0.01f * a;
        acc += a * s_wl[u];
    }
    outp[e] = 1.f / (1.f + __expf(-acc));
}

extern "C" void kernel_launch(void* const* d_in, const int* in_sizes, int n_in,
                              void* d_out, int out_size, void* d_ws, size_t ws_size,
                              hipStream_t stream)
{
    const float* x      = (const float*)d_in[0];
    const float* g0_wih = (const float*)d_in[1];
    const float* g0_whh = (const float*)d_in[2];
    const float* g0_bih = (const float*)d_in[3];
    const float* g0_bhh = (const float*)d_in[4];
    const float* g_wih  = (const float*)d_in[5];   // [4,120,40]
    const float* g_whh  = (const float*)d_in[6];   // [4,120,40]
    const float* g_bih  = (const float*)d_in[7];   // [4,120]
    const float* g_bhh  = (const float*)d_in[8];   // [4,120]
    const float* mlp_w1 = (const float*)d_in[9];   // [4,40,40]
    const float* mlp_b1 = (const float*)d_in[10];  // [4,40]
    const float* mlp_w2 = (const float*)d_in[11];  // [3,40,40]
    const float* mlp_b2 = (const float*)d_in[12];  // [3,40]
    const float* w_last = (const float*)d_in[13];  // [1,40]
    const float* b_last = (const float*)d_in[14];  // [1]

    const int B = in_sizes[0] / (T_STEPS * 20);
    float* out = (float*)d_out;

    // ws (halfs): [w1pad 3*3072][effpad 3*8192][g0pad 4096][g1pad 8192][whh16 5*4800] then xp
    __half* wsz    = (__half*)d_ws;
    __half* w1pad  = wsz;                       // 9216
    __half* effpad = wsz + 3 * 3072;            // 24576
    __half* g0pad  = wsz + 9216 + 3 * 8192;     // 4096
    __half* g1pad  = g0pad + 4096;              // 8192
    _Float16* whh16 = (_Float16*)(wsz + 46080); // 24000
    _Float16* xpbuf = (_Float16*)(wsz + 70080); // 140160 B of weights, 16B aligned
    const size_t ws_rem = ws_size - 70080 * sizeof(__half);

    for (int li = 0; li < 3; ++li)
        prep_pad<<<dim3(12), dim3(256), 0, stream>>>(
            mlp_w1 + li * 1600, mlp_b1 + li * 40, w1pad + li * 3072, 40, 40, 64);
    prep_pad<<<dim3(16), dim3(256), 0, stream>>>(g0_wih, g0_bih, g0pad, 120, 20, 32);
    prep_pad<<<dim3(32), dim3(256), 0, stream>>>(g_wih, g_bih, g1pad, 120, 40, 64);
    prep_eff<<<dim3(32, 3), dim3(256), 0, stream>>>(g_wih, g_bih, mlp_w2, mlp_b2, effpad);
    prep_f16cvt<<<dim3(19), dim3(256), 0, stream>>>(g0_whh, whh16, 4800);
    prep_f16cvt<<<dim3(75), dim3(256), 0, stream>>>(g_whh, whh16 + 4800, 19200);

    const size_t per_e = (size_t)ROWSP * GATES * sizeof(__half);  // padded element footprint
    int CB = B;
    while ((size_t)CB * per_e > ws_rem && CB > 64) CB >>= 1;

    for (int c = 0; c < B; c += CB) {
        const int  nrows = CB * T_STEPS;
        const dim3 pgrd(nrows / 512), pblk(256);
        const dim3 rgrd(CB), rblk(64);
        const float* xc = x + (size_t)c * T_STEPS * 20;

        precomp_mfma<0><<<pgrd, pblk, 0, stream>>>(
            xc, xpbuf, (const _Float16*)g0pad, nullptr, nrows);
        gru_recR<<<rgrd, rblk, 0, stream>>>((__half*)xpbuf, whh16, g0_bhh);

        precomp_mfma<1><<<pgrd, pblk, 0, stream>>>(
            xpbuf, xpbuf, (const _Float16*)g1pad, nullptr, nrows);
        gru_recR<<<rgrd, rblk, 0, stream>>>((__half*)xpbuf, whh16 + 4800, g_bhh + 0 * 120);

        for (int li = 0; li < 3; ++li) {
            precomp_mfma<2><<<pgrd, pblk, 0, stream>>>(
                xpbuf, xpbuf, (const _Float16*)(effpad + li * 8192),
                (const _Float16*)(w1pad + li * 3072), nrows);
            gru_recR<<<rgrd, rblk, 0, stream>>>(
                (__half*)xpbuf, whh16 + 4800 + (li + 1) * 4800, g_bhh + (li + 1) * 120);
        }

        final_head<<<dim3((CB + 255) / 256), dim3(256), 0, stream>>>(
            (const __half*)xpbuf, out + c,
            mlp_w1 + 3 * 1600, mlp_b1 + 3 * 40, w_last, b_last, CB);
    }
}